// Round 16
// baseline (695.508 us; speedup 1.0000x reference)
//
#include <hip/hip_runtime.h>
#include <hip/hip_bf16.h>

typedef __bf16 bf16_t;
typedef __bf16 bf16x4 __attribute__((ext_vector_type(4)));
typedef __bf16 bf16x8 __attribute__((ext_vector_type(8)));
typedef float  f32x4  __attribute__((ext_vector_type(4)));

static constexpr int TT = 8192;     // tokens (2*4096)
static constexpr int DD = 1024;
static constexpr int FF = 4096;
static constexpr int NSLOT = 2 * TT;  // 16384 (token, k) slots
static constexpr int GATE_BLKS = TT / 4;          // 2048
static constexpr int CVT_BLKS = 9437184 / 256;    // 36864
static constexpr int EG2_BLKS = 136 * 8;          // 1088
static constexpr int SG1_BLKS = 64 * 32;          // 2048

// routing int-array layout
#define R_COUNTS 0
#define R_OFFSET 8
#define R_TSTART 17
#define R_TOTAL  34
#define R_INTS   40

#define GLL(g, l) __builtin_amdgcn_global_load_lds( \
    (__attribute__((address_space(1))) void*)(g), \
    (__attribute__((address_space(3))) void*)(l), 16, 0, 0)

__device__ __forceinline__ float fast_gelu(float v) {
  float t = -1.5957691216f * v - 0.0713548162f * (v * v * v);
  return v / (1.f + __expf(t));
}

// ---------------------------------------------------------------- prep: gate (blocks 0..2047) + weight cvt
__global__ __launch_bounds__(256) void prep_kernel(const float* __restrict__ x,
                                                   const float* __restrict__ gw,
                                                   float* __restrict__ topkw,
                                                   int* __restrict__ slote,
                                                   bf16_t* __restrict__ xb,
                                                   const float* __restrict__ w1,
                                                   const float* __restrict__ w2,
                                                   const float* __restrict__ sw1,
                                                   const float* __restrict__ sw2,
                                                   bf16_t* __restrict__ wdst) {
  if ((int)blockIdx.x >= GATE_BLKS) {
    size_t i = (size_t)(blockIdx.x - GATE_BLKS) * 256 + threadIdx.x;
    const float* src;
    size_t off;
    if (i < 4194304)      { src = w1;  off = i; }
    else if (i < 8388608) { src = w2;  off = i - 4194304; }
    else if (i < 8912896) { src = sw1; off = i - 8388608; }
    else                  { src = sw2; off = i - 8912896; }
    const float4* s = reinterpret_cast<const float4*>(src) + off * 2;
    float4 a = s[0], b = s[1];
    bf16x8 v;
    v[0] = (bf16_t)a.x; v[1] = (bf16_t)a.y; v[2] = (bf16_t)a.z; v[3] = (bf16_t)a.w;
    v[4] = (bf16_t)b.x; v[5] = (bf16_t)b.y; v[6] = (bf16_t)b.z; v[7] = (bf16_t)b.w;
    *reinterpret_cast<bf16x8*>(wdst + i * 8) = v;
    return;
  }
  // ---- gate (no atomics; also emits xb)
  int wid = threadIdx.x >> 6, lane = threadIdx.x & 63;
  int t = blockIdx.x * 4 + wid;
  const float4* xv = reinterpret_cast<const float4*>(x + (size_t)t * DD) + lane * 4;
  const float4* gv = reinterpret_cast<const float4*>(gw);
  float acc[8];
  float4 xs[4];
#pragma unroll
  for (int e = 0; e < 8; ++e) acc[e] = 0.f;
#pragma unroll
  for (int i = 0; i < 4; ++i) {
    float4 xi = xv[i];
    xs[i] = xi;
#pragma unroll
    for (int e = 0; e < 8; ++e) {
      float4 g = gv[e * 256 + lane * 4 + i];
      acc[e] += xi.x * g.x + xi.y * g.y + xi.z * g.z + xi.w * g.w;
    }
  }
  {
    bf16x8 lo, hi;
    lo[0]=(bf16_t)xs[0].x; lo[1]=(bf16_t)xs[0].y; lo[2]=(bf16_t)xs[0].z; lo[3]=(bf16_t)xs[0].w;
    lo[4]=(bf16_t)xs[1].x; lo[5]=(bf16_t)xs[1].y; lo[6]=(bf16_t)xs[1].z; lo[7]=(bf16_t)xs[1].w;
    hi[0]=(bf16_t)xs[2].x; hi[1]=(bf16_t)xs[2].y; hi[2]=(bf16_t)xs[2].z; hi[3]=(bf16_t)xs[2].w;
    hi[4]=(bf16_t)xs[3].x; hi[5]=(bf16_t)xs[3].y; hi[6]=(bf16_t)xs[3].z; hi[7]=(bf16_t)xs[3].w;
    bf16_t* d = xb + (size_t)t * DD + lane * 16;
    *reinterpret_cast<bf16x8*>(d) = lo;
    *reinterpret_cast<bf16x8*>(d + 8) = hi;
  }
#pragma unroll
  for (int e = 0; e < 8; ++e)
    for (int off = 32; off; off >>= 1) acc[e] += __shfl_xor(acc[e], off, 64);
  if (lane == 0) {
    float m = acc[0];
#pragma unroll
    for (int e = 1; e < 8; ++e) m = fmaxf(m, acc[e]);
    float p[8], s = 0.f;
#pragma unroll
    for (int e = 0; e < 8; ++e) { p[e] = expf(acc[e] - m); s += p[e]; }
    float inv = 1.f / s;
#pragma unroll
    for (int e = 0; e < 8; ++e) p[e] *= inv;
    int e1 = 0; float b1v = p[0];
#pragma unroll
    for (int e = 1; e < 8; ++e) if (p[e] > b1v) { b1v = p[e]; e1 = e; }
    int e2 = -1; float b2v = -1.f;
#pragma unroll
    for (int e = 0; e < 8; ++e) if (e != e1 && p[e] > b2v) { b2v = p[e]; e2 = e; }
    topkw[2 * t] = b1v;  topkw[2 * t + 1] = b2v;
    slote[2 * t] = e1;   slote[2 * t + 1] = e2;
  }
}

// ---------------------------------------------------------------- fused routing (8 blocks, no atomics)
__global__ __launch_bounds__(256) void route_kernel(const int* __restrict__ slote,
                                                    int* __restrict__ routing,
                                                    int* __restrict__ perm,
                                                    int* __restrict__ pos) {
  __shared__ int sl[16384];   // 64 KB
  __shared__ int red[256];
  __shared__ int wtot[4];
  const int e = blockIdx.x;
  const int t = threadIdx.x;
  const int lane = t & 63, wid = t >> 6;

  for (int i = t; i < NSLOT; i += 256) sl[i] = slote[i];
  __syncthreads();

  int cnt[8];
#pragma unroll
  for (int ee = 0; ee < 8; ++ee) cnt[ee] = 0;
  for (int i = t; i < NSLOT; i += 256) ++cnt[sl[i]];

  int tot[8];
#pragma unroll
  for (int ee = 0; ee < 8; ++ee) {
    red[t] = cnt[ee];
    __syncthreads();
    for (int s = 128; s; s >>= 1) {
      if (t < s) red[t] += red[t + s];
      __syncthreads();
    }
    tot[ee] = red[0];
    __syncthreads();
  }

  int offarr[9], tstart[9];
  {
    int off = 0, tts = 0;
#pragma unroll
    for (int ee = 0; ee < 8; ++ee) {
      offarr[ee] = off; tstart[ee] = tts;
      off += tot[ee]; tts += (tot[ee] + 127) >> 7;
    }
    offarr[8] = off; tstart[8] = tts;
  }
  if (e == 0 && t == 0) {
#pragma unroll
    for (int ee = 0; ee < 8; ++ee) routing[R_COUNTS + ee] = tot[ee];
#pragma unroll
    for (int ee = 0; ee < 9; ++ee) {
      routing[R_OFFSET + ee] = offarr[ee];
      routing[R_TSTART + ee] = tstart[ee];
    }
    routing[R_TOTAL] = tstart[8];
  }

  int running = offarr[e];
  for (int base = 0; base < NSLOT; base += 256) {
    int s = base + t;
    bool m = (sl[s] == e);
    unsigned long long mask = __ballot(m);
    int wrank = __popcll(mask & ((1ull << lane) - 1ull));
    if (lane == 0) wtot[wid] = __popcll(mask);
    __syncthreads();
    int wpre = 0;
#pragma unroll
    for (int w = 0; w < 4; ++w) if (w < wid) wpre += wtot[w];
    int totb = wtot[0] + wtot[1] + wtot[2] + wtot[3];
    if (m) {
      int pp = running + wpre + wrank;
      perm[pp] = s;
      pos[s] = pp;
    }
    running += totb;
    __syncthreads();
  }
}

// ---------------------------------------------------------------- GEMM body (BK=32, 16 KB LDS, 8 blocks/CU)
// 128x128 tile, BK=32, 256 threads / 4 waves (2x2), SINGLE 16 KB LDS buffer,
// loop = {STAGE(kt); sync; ds_read+MFMA; sync}. Row = 64 B = 4 chunks of 16 B;
// swizzle phys_chunk = log_chunk ^ ((row>>1)&3), both sides (R4-verified involution).
// MODE 0: expert G1 (A via perm, K=1024) -> fast_gelu -> H (bf16)
// MODE 1: expert G2 (A = H rows, K=4096) -> w_slot*(acc+b2) -> slotb (bf16)
// MODE 2: shared G1 (A = x direct, K=1024) -> fast_gelu -> H (bf16)
// MODE 3: shared G2 (A = H rows, K=4096) -> out = acc+sb2+slotb[pos0]+slotb[pos1]
template <int MODE>
__device__ __forceinline__ void gemm_body(
    int vbid, int nwg, bf16_t* lds,
    const bf16_t* __restrict__ A, const bf16_t* __restrict__ Bw,
    const float* __restrict__ bias, bf16_t* __restrict__ Hout,
    float* __restrict__ out, const int* __restrict__ routing,
    const int* __restrict__ perm, const float* __restrict__ topkw,
    const int* __restrict__ pos, const bf16_t* __restrict__ slotb) {
  constexpr bool EXPERT = (MODE < 2);
  constexpr int K = (MODE == 0 || MODE == 2) ? 1024 : 4096;
  constexpr int NTOT = (MODE == 0 || MODE == 2) ? 4096 : 1024;
  constexpr int NT = NTOT / 128;   // 32 or 8 (pow2)
  constexpr int NKT = K / 32;      // 32 or 128
  constexpr int OUTD = (MODE == 0 || MODE == 2) ? FF : DD;

  const int t = threadIdx.x;
  const int lane = t & 63;
  const int wid = t >> 6;          // 0..3
  const int wm = wid >> 1;         // 0..1
  const int wn = wid & 1;          // 0..1

  const int q = nwg >> 3, r = nwg & 7;
  const int xcd = vbid & 7, bi = vbid >> 3;
  const int swz = (xcd < r ? xcd * (q + 1) : r * (q + 1) + (xcd - r) * q) + bi;
  const int mt = swz / NT;
  const int nt = swz & (NT - 1);

  int row0, valid, eidx = 0;
  if constexpr (EXPERT) {
    if (mt >= routing[R_TOTAL]) return;
    int e = 0;
    while (e < 7 && routing[R_TSTART + e + 1] <= mt) ++e;
    eidx = e;
    int lm = mt - routing[R_TSTART + e];
    row0 = routing[R_OFFSET + e] + lm * 128;
    valid = min(128, routing[R_COUNTS + e] - lm * 128);
  } else {
    row0 = mt * 128;
    valid = 128;
  }

  const bf16_t* Bexp = Bw + (EXPERT ? (size_t)eidx * NTOT * K : 0);
  const float* biasp = bias + (EXPERT ? eidx * NTOT : 0);

  // ---- staging: 4 GLL/thread per K-tile (A 8 KB + B 8 KB).
  // thread t: row = 64g + (t>>2), phys chunk = t&3;
  // logical source chunk = (t&3) ^ ((row>>1)&3) = (t&3) ^ ((t>>3)&3)
  const int sr = t >> 2;                      // 0..63
  const int lc = (t & 3) ^ ((t >> 3) & 3);
  const bf16_t* aS[2];
  const bf16_t* bS[2];
#pragma unroll
  for (int g = 0; g < 2; ++g) {
    int lr = g * 64 + sr;                     // 0..127
    int gr;
    if constexpr (MODE == 0) {
      gr = perm[row0 + min(lr, valid - 1)] >> 1;
    } else if constexpr (MODE == 1) {
      gr = row0 + min(lr, valid - 1);
    } else {
      gr = row0 + lr;
    }
    aS[g] = A + (size_t)gr * K + lc * 8;
    bS[g] = Bexp + (size_t)(nt * 128 + lr) * K + lc * 8;
  }
  bf16_t* const aD = lds + (t << 3);          // + g*2048
  bf16_t* const bD = aD + 4096;

  const int l15 = lane & 15, lq = lane >> 4;

  f32x4 acc[4][4];
#pragma unroll
  for (int m = 0; m < 4; ++m)
#pragma unroll
    for (int n = 0; n < 4; ++n) acc[m][n] = f32x4{0.f, 0.f, 0.f, 0.f};

  for (int kt = 0; kt < NKT; ++kt) {
    const size_t kof = (size_t)kt * 32;
    GLL(aS[0] + kof, aD);
    GLL(aS[1] + kof, aD + 2048);
    GLL(bS[0] + kof, bD);
    GLL(bS[1] + kof, bD + 2048);
    __syncthreads();   // drains vmcnt: tile kt fully in LDS

    bf16x8 af[4], bfr[4];
#pragma unroll
    for (int m = 0; m < 4; ++m) {
      int ra = wm * 64 + m * 16 + l15;
      int ph = lq ^ ((ra >> 1) & 3);
      af[m] = *reinterpret_cast<const bf16x8*>(&lds[ra * 32 + ph * 8]);
    }
#pragma unroll
    for (int n = 0; n < 4; ++n) {
      int rb = wn * 64 + n * 16 + l15;
      int ph = lq ^ ((rb >> 1) & 3);
      bfr[n] = *reinterpret_cast<const bf16x8*>(&lds[4096 + rb * 32 + ph * 8]);
    }
    __builtin_amdgcn_s_setprio(1);
#pragma unroll
    for (int m = 0; m < 4; ++m)
#pragma unroll
      for (int n = 0; n < 4; ++n)
        acc[m][n] = __builtin_amdgcn_mfma_f32_16x16x32_bf16(af[m], bfr[n], acc[m][n], 0, 0, 0);
    __builtin_amdgcn_s_setprio(0);
    __syncthreads();   // all reads done before next STAGE overwrites
  }

  float bc[4];
#pragma unroll
  for (int n = 0; n < 4; ++n) bc[n] = biasp[nt * 128 + wn * 64 + n * 16 + l15];

  // ---- epilogue via LDS transpose (16 KB scratch): coalesced vector stores.
  // C/D frag: col = lane&15, row = (lane>>4)*4 + rr  [m89-verified]
  if constexpr (MODE != 3) {
    bf16_t* scr = lds;   // 64 x 128 bf16 = 16 KB per half
#pragma unroll
    for (int h = 0; h < 2; ++h) {
      __syncthreads();
      if (wm == h) {
        float wsl[4][4];
        if constexpr (MODE == 1) {
#pragma unroll
          for (int m = 0; m < 4; ++m)
#pragma unroll
            for (int rr = 0; rr < 4; ++rr) {
              int lr = h * 64 + m * 16 + lq * 4 + rr;
              wsl[m][rr] = topkw[perm[row0 + min(lr, valid - 1)]];
            }
        }
#pragma unroll
        for (int m = 0; m < 4; ++m)
#pragma unroll
          for (int n = 0; n < 4; ++n)
#pragma unroll
            for (int rr = 0; rr < 4; ++rr) {
              float v = acc[m][n][rr] + bc[n];
              float o;
              if constexpr (MODE == 1) o = wsl[m][rr] * v;
              else                     o = fast_gelu(v);
              scr[(m * 16 + lq * 4 + rr) * 128 + wn * 64 + n * 16 + l15] = (bf16_t)o;
            }
      }
      __syncthreads();
#pragma unroll
      for (int i = 0; i < 4; ++i) {
        int c = t + i * 256;
        int rowp = c >> 4, cc = c & 15;
        int lr = h * 64 + rowp;
        if (lr < valid) {
          bf16x8 v8 = *reinterpret_cast<const bf16x8*>(&scr[rowp * 128 + cc * 8]);
          *reinterpret_cast<bf16x8*>(&Hout[(size_t)(row0 + lr) * OUTD + nt * 128 + cc * 8]) = v8;
        }
      }
    }
  } else {
    float* scr = reinterpret_cast<float*>(lds);   // 32 x 128 f32 = 16 KB per quarter
#pragma unroll
    for (int h4 = 0; h4 < 4; ++h4) {
      __syncthreads();
      if (wm == (h4 >> 1)) {
        const int mbase = (h4 & 1) * 2;
#pragma unroll
        for (int mm = 0; mm < 2; ++mm)
#pragma unroll
          for (int n = 0; n < 4; ++n)
#pragma unroll
            for (int rr = 0; rr < 4; ++rr)
              scr[(mm * 16 + lq * 4 + rr) * 128 + wn * 64 + n * 16 + l15] =
                  acc[mbase + mm][n][rr] + bc[n];
      }
      __syncthreads();
#pragma unroll
      for (int i = 0; i < 4; ++i) {
        int c = t + i * 256;                 // 0..1023 float4 chunks (32x128 f32)
        int rowp = c >> 5, cc = c & 31;
        int lr = (h4 >> 1) * 64 + (h4 & 1) * 32 + rowp;
        int gp = row0 + lr;
        int p0 = pos[2 * gp], p1 = pos[2 * gp + 1];
        float4 v4 = *reinterpret_cast<const float4*>(&scr[rowp * 128 + cc * 4]);
        bf16x4 s0 = *reinterpret_cast<const bf16x4*>(&slotb[(size_t)p0 * DD + nt * 128 + cc * 4]);
        bf16x4 s1 = *reinterpret_cast<const bf16x4*>(&slotb[(size_t)p1 * DD + nt * 128 + cc * 4]);
        v4.x += (float)s0[0] + (float)s1[0];
        v4.y += (float)s0[1] + (float)s1[1];
        v4.z += (float)s0[2] + (float)s1[2];
        v4.w += (float)s0[3] + (float)s1[3];
        *reinterpret_cast<float4*>(&out[(size_t)gp * OUTD + nt * 128 + cc * 4]) = v4;
      }
    }
  }
}

// ---------------------------------------------------------------- kernels
template <int MODE>
__global__ __launch_bounds__(256, 4) void gemm_single(
    const bf16_t* __restrict__ A, const bf16_t* __restrict__ Bw,
    const float* __restrict__ bias, bf16_t* __restrict__ Hout,
    float* __restrict__ out, const int* __restrict__ routing,
    const int* __restrict__ perm, const float* __restrict__ topkw,
    const int* __restrict__ pos, const bf16_t* __restrict__ slotb) {
  __shared__ __align__(16) bf16_t lds[8192];   // 16 KB
  gemm_body<MODE>(blockIdx.x, gridDim.x, lds, A, Bw, bias, Hout, out,
                  routing, perm, topkw, pos, slotb);
}

// eG2 (blocks 0..EG2_BLKS-1) || sG1 (rest). sG1 writes its own sHbuf.
__global__ __launch_bounds__(256, 4) void gemm_eg2_sg1(
    const bf16_t* __restrict__ Hexp, const bf16_t* __restrict__ w2b,
    const float* __restrict__ b2, bf16_t* __restrict__ slotb,
    const bf16_t* __restrict__ xb, const bf16_t* __restrict__ sw1b,
    const float* __restrict__ sb1, bf16_t* __restrict__ sHbuf,
    const int* __restrict__ routing, const int* __restrict__ perm,
    const float* __restrict__ topkw) {
  __shared__ __align__(16) bf16_t lds[8192];   // 16 KB
  if ((int)blockIdx.x < EG2_BLKS) {
    gemm_body<1>(blockIdx.x, EG2_BLKS, lds, Hexp, w2b, b2, slotb, nullptr,
                 routing, perm, topkw, nullptr, nullptr);
  } else {
    gemm_body<2>(blockIdx.x - EG2_BLKS, SG1_BLKS, lds, xb, sw1b, sb1, sHbuf,
                 nullptr, routing, perm, nullptr, nullptr, nullptr);
  }
}

// ---------------------------------------------------------------- launch
extern "C" void kernel_launch(void* const* d_in, const int* in_sizes, int n_in,
                              void* d_out, int out_size, void* d_ws, size_t ws_size,
                              hipStream_t stream) {
  const float* x   = (const float*)d_in[0];
  const float* gw  = (const float*)d_in[1];
  const float* w1  = (const float*)d_in[2];
  const float* b1  = (const float*)d_in[3];
  const float* w2  = (const float*)d_in[4];
  const float* b2  = (const float*)d_in[5];
  const float* sw1 = (const float*)d_in[6];
  const float* sb1 = (const float*)d_in[7];
  const float* sw2 = (const float*)d_in[8];
  const float* sb2 = (const float*)d_in[9];
  float* out = (float*)d_out;

  char* ws = (char*)d_ws;
  bf16_t* xb    = (bf16_t*)(ws);                          // 16 MB  [alive through sG1]
  bf16_t* w1b   = (bf16_t*)(ws + ((size_t)16 << 20));     // 64 MB  [dead after eG1]
  bf16_t* w2b   = (bf16_t*)(ws + ((size_t)80 << 20));     // 64 MB  [dead after eG2]
  bf16_t* sw1b  = (bf16_t*)(ws + ((size_t)144 << 20));    // 8 MB
  bf16_t* sw2b  = (bf16_t*)(ws + ((size_t)152 << 20));    // 8 MB
  bf16_t* Hbuf  = (bf16_t*)(ws + ((size_t)160 << 20));    // 128 MB (16384 x 4096 bf16)
  bf16_t* slotb = (bf16_t*)(ws + ((size_t)16 << 20));     // 32 MB bf16, reuses w1b (dead by eG2)
  float*  topkw = (float*)(ws + ((size_t)288 << 20));     // 64 KB
  int*    slote = (int*)(ws + ((size_t)288 << 20) + 65536);
  int*    perm  = (int*)(ws + ((size_t)288 << 20) + 2 * 65536);
  int*    pos   = (int*)(ws + ((size_t)288 << 20) + 3 * 65536);
  int*    routing = (int*)(ws + ((size_t)288 << 20) + 4 * 65536);

  // optional separate shared-H buffer (64 MB at 304 MB) enabling eG2 || sG1
  const bool bigws = ws_size >= ((size_t)368 << 20);
  bf16_t* sHbuf = bigws ? (bf16_t*)(ws + ((size_t)304 << 20)) : Hbuf;

  // gate + weight conversions in one launch
  prep_kernel<<<GATE_BLKS + CVT_BLKS, 256, 0, stream>>>(x, gw, topkw, slote, xb,
                                                        w1, w2, sw1, sw2, w1b);
  // routing (no global atomics anywhere)
  route_kernel<<<8, 256, 0, stream>>>(slote, routing, perm, pos);

  // expert G1 first (frees w1b for slotb)
  gemm_single<0><<<136 * 32, 256, 0, stream>>>(xb, w1b, b1, Hbuf, nullptr, routing,
                                               perm, nullptr, nullptr, nullptr);
  if (bigws) {
    // eG2 || sG1 concurrently (sG1 writes sHbuf, no aliasing with Hbuf)
    gemm_eg2_sg1<<<EG2_BLKS + SG1_BLKS, 256, 0, stream>>>(Hbuf, w2b, b2, slotb,
                                                          xb, sw1b, sb1, sHbuf,
                                                          routing, perm, topkw);
  } else {
    gemm_single<1><<<EG2_BLKS, 256, 0, stream>>>(Hbuf, w2b, b2, slotb, nullptr,
                                                 routing, perm, topkw, nullptr, nullptr);
    gemm_single<2><<<SG1_BLKS, 256, 0, stream>>>(xb, sw1b, sb1, Hbuf, nullptr,
                                                 routing, perm, nullptr, nullptr, nullptr);
  }
  // shared G2 with fused combine
  gemm_single<3><<<64 * 8, 256, 0, stream>>>(sHbuf, sw2b, sb2, nullptr, out, routing,
                                             perm, nullptr, pos, slotb);
}

// Round 17
// 632.751 us; speedup vs baseline: 1.0992x; 1.0992x over previous
//
#include <hip/hip_runtime.h>
#include <hip/hip_bf16.h>

typedef __bf16 bf16_t;
typedef __bf16 bf16x4 __attribute__((ext_vector_type(4)));
typedef __bf16 bf16x8 __attribute__((ext_vector_type(8)));
typedef float  f32x4  __attribute__((ext_vector_type(4)));

static constexpr int TT = 8192;     // tokens (2*4096)
static constexpr int DD = 1024;
static constexpr int FF = 4096;
static constexpr int NSLOT = 2 * TT;  // 16384 (token, k) slots
static constexpr int GATE_BLKS = TT / 4;          // 2048
static constexpr int CVT_BLKS = 9437184 / 256;    // 36864
static constexpr int EG2_BLKS = 136 * 8;          // 1088
static constexpr int SG1_BLKS = 64 * 32;          // 2048

// routing int-array layout
#define R_COUNTS 0
#define R_OFFSET 8
#define R_TSTART 17
#define R_TOTAL  34
#define R_INTS   40

#define GLL(g, l) __builtin_amdgcn_global_load_lds( \
    (__attribute__((address_space(1))) void*)(g), \
    (__attribute__((address_space(3))) void*)(l), 16, 0, 0)

__device__ __forceinline__ float fast_gelu(float v) {
  float t = -1.5957691216f * v - 0.0713548162f * (v * v * v);
  return v / (1.f + __expf(t));
}

// ---------------------------------------------------------------- prep: gate (blocks 0..2047) + weight cvt
__global__ __launch_bounds__(256) void prep_kernel(const float* __restrict__ x,
                                                   const float* __restrict__ gw,
                                                   float* __restrict__ topkw,
                                                   int* __restrict__ slote,
                                                   bf16_t* __restrict__ xb,
                                                   const float* __restrict__ w1,
                                                   const float* __restrict__ w2,
                                                   const float* __restrict__ sw1,
                                                   const float* __restrict__ sw2,
                                                   bf16_t* __restrict__ wdst) {
  if ((int)blockIdx.x >= GATE_BLKS) {
    // ---- weight convert: one 8-elem chunk per thread
    size_t i = (size_t)(blockIdx.x - GATE_BLKS) * 256 + threadIdx.x;
    const float* src;
    size_t off;
    if (i < 4194304)      { src = w1;  off = i; }
    else if (i < 8388608) { src = w2;  off = i - 4194304; }
    else if (i < 8912896) { src = sw1; off = i - 8388608; }
    else                  { src = sw2; off = i - 8912896; }
    const float4* s = reinterpret_cast<const float4*>(src) + off * 2;
    float4 a = s[0], b = s[1];
    bf16x8 v;
    v[0] = (bf16_t)a.x; v[1] = (bf16_t)a.y; v[2] = (bf16_t)a.z; v[3] = (bf16_t)a.w;
    v[4] = (bf16_t)b.x; v[5] = (bf16_t)b.y; v[6] = (bf16_t)b.z; v[7] = (bf16_t)b.w;
    *reinterpret_cast<bf16x8*>(wdst + i * 8) = v;
    return;
  }
  // ---- gate (no atomics; also emits xb)
  int wid = threadIdx.x >> 6, lane = threadIdx.x & 63;
  int t = blockIdx.x * 4 + wid;
  const float4* xv = reinterpret_cast<const float4*>(x + (size_t)t * DD) + lane * 4;
  const float4* gv = reinterpret_cast<const float4*>(gw);
  float acc[8];
  float4 xs[4];
#pragma unroll
  for (int e = 0; e < 8; ++e) acc[e] = 0.f;
#pragma unroll
  for (int i = 0; i < 4; ++i) {
    float4 xi = xv[i];
    xs[i] = xi;
#pragma unroll
    for (int e = 0; e < 8; ++e) {
      float4 g = gv[e * 256 + lane * 4 + i];
      acc[e] += xi.x * g.x + xi.y * g.y + xi.z * g.z + xi.w * g.w;
    }
  }
  {
    bf16x8 lo, hi;
    lo[0]=(bf16_t)xs[0].x; lo[1]=(bf16_t)xs[0].y; lo[2]=(bf16_t)xs[0].z; lo[3]=(bf16_t)xs[0].w;
    lo[4]=(bf16_t)xs[1].x; lo[5]=(bf16_t)xs[1].y; lo[6]=(bf16_t)xs[1].z; lo[7]=(bf16_t)xs[1].w;
    hi[0]=(bf16_t)xs[2].x; hi[1]=(bf16_t)xs[2].y; hi[2]=(bf16_t)xs[2].z; hi[3]=(bf16_t)xs[2].w;
    hi[4]=(bf16_t)xs[3].x; hi[5]=(bf16_t)xs[3].y; hi[6]=(bf16_t)xs[3].z; hi[7]=(bf16_t)xs[3].w;
    bf16_t* d = xb + (size_t)t * DD + lane * 16;
    *reinterpret_cast<bf16x8*>(d) = lo;
    *reinterpret_cast<bf16x8*>(d + 8) = hi;
  }
#pragma unroll
  for (int e = 0; e < 8; ++e)
    for (int off = 32; off; off >>= 1) acc[e] += __shfl_xor(acc[e], off, 64);
  if (lane == 0) {
    float m = acc[0];
#pragma unroll
    for (int e = 1; e < 8; ++e) m = fmaxf(m, acc[e]);
    float p[8], s = 0.f;
#pragma unroll
    for (int e = 0; e < 8; ++e) { p[e] = expf(acc[e] - m); s += p[e]; }
    float inv = 1.f / s;
#pragma unroll
    for (int e = 0; e < 8; ++e) p[e] *= inv;
    int e1 = 0; float b1v = p[0];
#pragma unroll
    for (int e = 1; e < 8; ++e) if (p[e] > b1v) { b1v = p[e]; e1 = e; }
    int e2 = -1; float b2v = -1.f;
#pragma unroll
    for (int e = 0; e < 8; ++e) if (e != e1 && p[e] > b2v) { b2v = p[e]; e2 = e; }
    topkw[2 * t] = b1v;  topkw[2 * t + 1] = b2v;
    slote[2 * t] = e1;   slote[2 * t + 1] = e2;
  }
}

// ---------------------------------------------------------------- fused routing (8 blocks, no atomics)
__global__ __launch_bounds__(256) void route_kernel(const int* __restrict__ slote,
                                                    int* __restrict__ routing,
                                                    int* __restrict__ perm,
                                                    int* __restrict__ pos) {
  __shared__ int sl[16384];   // 64 KB
  __shared__ int red[256];
  __shared__ int wtot[4];
  const int e = blockIdx.x;
  const int t = threadIdx.x;
  const int lane = t & 63, wid = t >> 6;

  for (int i = t; i < NSLOT; i += 256) sl[i] = slote[i];
  __syncthreads();

  int cnt[8];
#pragma unroll
  for (int ee = 0; ee < 8; ++ee) cnt[ee] = 0;
  for (int i = t; i < NSLOT; i += 256) ++cnt[sl[i]];

  int tot[8];
#pragma unroll
  for (int ee = 0; ee < 8; ++ee) {
    red[t] = cnt[ee];
    __syncthreads();
    for (int s = 128; s; s >>= 1) {
      if (t < s) red[t] += red[t + s];
      __syncthreads();
    }
    tot[ee] = red[0];
    __syncthreads();
  }

  int offarr[9], tstart[9];
  {
    int off = 0, tts = 0;
#pragma unroll
    for (int ee = 0; ee < 8; ++ee) {
      offarr[ee] = off; tstart[ee] = tts;
      off += tot[ee]; tts += (tot[ee] + 127) >> 7;
    }
    offarr[8] = off; tstart[8] = tts;
  }
  if (e == 0 && t == 0) {
#pragma unroll
    for (int ee = 0; ee < 8; ++ee) routing[R_COUNTS + ee] = tot[ee];
#pragma unroll
    for (int ee = 0; ee < 9; ++ee) {
      routing[R_OFFSET + ee] = offarr[ee];
      routing[R_TSTART + ee] = tstart[ee];
    }
    routing[R_TOTAL] = tstart[8];
  }

  int running = offarr[e];
  for (int base = 0; base < NSLOT; base += 256) {
    int s = base + t;
    bool m = (sl[s] == e);
    unsigned long long mask = __ballot(m);
    int wrank = __popcll(mask & ((1ull << lane) - 1ull));
    if (lane == 0) wtot[wid] = __popcll(mask);
    __syncthreads();
    int wpre = 0;
#pragma unroll
    for (int w = 0; w < 4; ++w) if (w < wid) wpre += wtot[w];
    int totb = wtot[0] + wtot[1] + wtot[2] + wtot[3];
    if (m) {
      int pp = running + wpre + wrank;
      perm[pp] = s;
      pos[s] = pp;
    }
    running += totb;
    __syncthreads();
  }
}

// ---------------------------------------------------------------- GEMM body (m97 replica loop; frozen)
// 128x128 tile, BK=64, 256 threads / 4 waves (2x2), SINGLE 32 KB LDS buffer.
// Swizzle phys_chunk = log_chunk ^ (row&7), both sides. BK axis closed: BK=32
// (R16) doubled barrier count and lost 22% MfmaUtil; BK=64 is the measured optimum.
// MODE 0: expert G1 (A via perm, K=1024) -> fast_gelu -> H (bf16)
// MODE 1: expert G2 (A = H rows, K=4096) -> w_slot*(acc+b2) -> slotb (bf16)
// MODE 2: shared G1 (A = x direct, K=1024) -> fast_gelu -> H (bf16)
// MODE 3: shared G2 (A = H rows, K=4096) -> out = acc+sb2+slotb[pos0]+slotb[pos1]
template <int MODE>
__device__ __forceinline__ void gemm_body(
    int vbid, int nwg, bf16_t* lds,
    const bf16_t* __restrict__ A, const bf16_t* __restrict__ Bw,
    const float* __restrict__ bias, bf16_t* __restrict__ Hout,
    float* __restrict__ out, const int* __restrict__ routing,
    const int* __restrict__ perm, const float* __restrict__ topkw,
    const int* __restrict__ pos, const bf16_t* __restrict__ slotb) {
  constexpr bool EXPERT = (MODE < 2);
  constexpr int K = (MODE == 0 || MODE == 2) ? 1024 : 4096;
  constexpr int NTOT = (MODE == 0 || MODE == 2) ? 4096 : 1024;
  constexpr int NT = NTOT / 128;   // 32 or 8 (pow2)
  constexpr int NKT = K / 64;      // 16 or 64
  constexpr int OUTD = (MODE == 0 || MODE == 2) ? FF : DD;

  const int t = threadIdx.x;
  const int lane = t & 63;
  const int wid = t >> 6;          // 0..3
  const int wm = wid >> 1;         // 0..1
  const int wn = wid & 1;          // 0..1

  const int q = nwg >> 3, r = nwg & 7;
  const int xcd = vbid & 7, bi = vbid >> 3;
  const int swz = (xcd < r ? xcd * (q + 1) : r * (q + 1) + (xcd - r) * q) + bi;
  const int mt = swz / NT;
  const int nt = swz & (NT - 1);

  int row0, valid, eidx = 0;
  if constexpr (EXPERT) {
    if (mt >= routing[R_TOTAL]) return;
    int e = 0;
    while (e < 7 && routing[R_TSTART + e + 1] <= mt) ++e;
    eidx = e;
    int lm = mt - routing[R_TSTART + e];
    row0 = routing[R_OFFSET + e] + lm * 128;
    valid = min(128, routing[R_COUNTS + e] - lm * 128);
  } else {
    row0 = mt * 128;
    valid = 128;
  }

  const bf16_t* Bexp = Bw + (EXPERT ? (size_t)eidx * NTOT * K : 0);
  const float* biasp = bias + (EXPERT ? eidx * NTOT : 0);

  const int sub = t >> 3;                     // 0..31
  const int lc = (t & 7) ^ (sub & 7);
  const bf16_t* aS[4];
  const bf16_t* bS[4];
#pragma unroll
  for (int i = 0; i < 4; ++i) {
    int lr = sub + i * 32;                    // 0..127
    int gr;
    if constexpr (MODE == 0) {
      gr = perm[row0 + min(lr, valid - 1)] >> 1;
    } else if constexpr (MODE == 1) {
      gr = row0 + min(lr, valid - 1);
    } else {
      gr = row0 + lr;
    }
    aS[i] = A + (size_t)gr * K + lc * 8;
    bS[i] = Bexp + (size_t)(nt * 128 + lr) * K + lc * 8;
  }
  bf16_t* const aD = lds + (sub << 6) + ((t & 7) << 3);
  bf16_t* const bD = aD + 8192;

  const int l15 = lane & 15, lq = lane >> 4;

  f32x4 acc[4][4];
#pragma unroll
  for (int m = 0; m < 4; ++m)
#pragma unroll
    for (int n = 0; n < 4; ++n) acc[m][n] = f32x4{0.f, 0.f, 0.f, 0.f};

  for (int kt = 0; kt < NKT; ++kt) {
    const size_t kof = (size_t)kt * 64;
#pragma unroll
    for (int i = 0; i < 4; ++i) {
      GLL(aS[i] + kof, aD + i * 2048);
      GLL(bS[i] + kof, bD + i * 2048);
    }
    __syncthreads();

#pragma unroll
    for (int kk = 0; kk < 2; ++kk) {
      bf16x8 af[4], bfr[4];
#pragma unroll
      for (int m = 0; m < 4; ++m) {
        int ra = wm * 64 + m * 16 + l15;
        int ph = (kk * 4 + lq) ^ (ra & 7);
        af[m] = *reinterpret_cast<const bf16x8*>(&lds[ra * 64 + ph * 8]);
      }
#pragma unroll
      for (int n = 0; n < 4; ++n) {
        int rb = wn * 64 + n * 16 + l15;
        int ph = (kk * 4 + lq) ^ (rb & 7);
        bfr[n] = *reinterpret_cast<const bf16x8*>(&lds[8192 + rb * 64 + ph * 8]);
      }
      __builtin_amdgcn_s_setprio(1);
#pragma unroll
      for (int m = 0; m < 4; ++m)
#pragma unroll
        for (int n = 0; n < 4; ++n)
          acc[m][n] = __builtin_amdgcn_mfma_f32_16x16x32_bf16(af[m], bfr[n], acc[m][n], 0, 0, 0);
      __builtin_amdgcn_s_setprio(0);
    }
    __syncthreads();
  }

  float bc[4];
#pragma unroll
  for (int n = 0; n < 4; ++n) bc[n] = biasp[nt * 128 + wn * 64 + n * 16 + l15];

  // ---- epilogue via LDS transpose: coalesced vector stores.
  if constexpr (MODE != 3) {
    bf16_t* scr = lds;   // 64 x 128 bf16 = 16 KB per half
#pragma unroll
    for (int h = 0; h < 2; ++h) {
      __syncthreads();
      if (wm == h) {
        float wsl[4][4];
        if constexpr (MODE == 1) {
#pragma unroll
          for (int m = 0; m < 4; ++m)
#pragma unroll
            for (int rr = 0; rr < 4; ++rr) {
              int lr = h * 64 + m * 16 + lq * 4 + rr;
              wsl[m][rr] = topkw[perm[row0 + min(lr, valid - 1)]];
            }
        }
#pragma unroll
        for (int m = 0; m < 4; ++m)
#pragma unroll
          for (int n = 0; n < 4; ++n)
#pragma unroll
            for (int rr = 0; rr < 4; ++rr) {
              float v = acc[m][n][rr] + bc[n];
              float o;
              if constexpr (MODE == 1) o = wsl[m][rr] * v;
              else                     o = fast_gelu(v);
              scr[(m * 16 + lq * 4 + rr) * 128 + wn * 64 + n * 16 + l15] = (bf16_t)o;
            }
      }
      __syncthreads();
#pragma unroll
      for (int i = 0; i < 4; ++i) {
        int c = t + i * 256;
        int rowp = c >> 4, cc = c & 15;
        int lr = h * 64 + rowp;
        if (lr < valid) {
          bf16x8 v8 = *reinterpret_cast<const bf16x8*>(&scr[rowp * 128 + cc * 8]);
          *reinterpret_cast<bf16x8*>(&Hout[(size_t)(row0 + lr) * OUTD + nt * 128 + cc * 8]) = v8;
        }
      }
    }
  } else {
    float* scr = reinterpret_cast<float*>(lds);   // 64 x 128 f32 = 32 KB per half
#pragma unroll
    for (int h = 0; h < 2; ++h) {
      __syncthreads();
      if (wm == h) {
#pragma unroll
        for (int m = 0; m < 4; ++m)
#pragma unroll
          for (int n = 0; n < 4; ++n)
#pragma unroll
            for (int rr = 0; rr < 4; ++rr)
              scr[(m * 16 + lq * 4 + rr) * 128 + wn * 64 + n * 16 + l15] = acc[m][n][rr] + bc[n];
      }
      __syncthreads();
#pragma unroll
      for (int i = 0; i < 8; ++i) {
        int c = t + i * 256;
        int rowp = c >> 5, cc = c & 31;
        int lr = h * 64 + rowp;
        int gp = row0 + lr;
        int p0 = pos[2 * gp], p1 = pos[2 * gp + 1];
        float4 v4 = *reinterpret_cast<const float4*>(&scr[rowp * 128 + cc * 4]);
        bf16x4 s0 = *reinterpret_cast<const bf16x4*>(&slotb[(size_t)p0 * DD + nt * 128 + cc * 4]);
        bf16x4 s1 = *reinterpret_cast<const bf16x4*>(&slotb[(size_t)p1 * DD + nt * 128 + cc * 4]);
        v4.x += (float)s0[0] + (float)s1[0];
        v4.y += (float)s0[1] + (float)s1[1];
        v4.z += (float)s0[2] + (float)s1[2];
        v4.w += (float)s0[3] + (float)s1[3];
        *reinterpret_cast<float4*>(&out[(size_t)gp * OUTD + nt * 128 + cc * 4]) = v4;
      }
    }
  }
}

// ---------------------------------------------------------------- kernels
template <int MODE>
__global__ __launch_bounds__(256, 4) void gemm_single(
    const bf16_t* __restrict__ A, const bf16_t* __restrict__ Bw,
    const float* __restrict__ bias, bf16_t* __restrict__ Hout,
    float* __restrict__ out, const int* __restrict__ routing,
    const int* __restrict__ perm, const float* __restrict__ topkw,
    const int* __restrict__ pos, const bf16_t* __restrict__ slotb) {
  __shared__ __align__(16) bf16_t lds[16384];
  gemm_body<MODE>(blockIdx.x, gridDim.x, lds, A, Bw, bias, Hout, out,
                  routing, perm, topkw, pos, slotb);
}

// eG2 (blocks 0..EG2_BLKS-1) || sG1 (rest). sG1 writes its own sHbuf.
__global__ __launch_bounds__(256, 4) void gemm_eg2_sg1(
    const bf16_t* __restrict__ Hexp, const bf16_t* __restrict__ w2b,
    const float* __restrict__ b2, bf16_t* __restrict__ slotb,
    const bf16_t* __restrict__ xb, const bf16_t* __restrict__ sw1b,
    const float* __restrict__ sb1, bf16_t* __restrict__ sHbuf,
    const int* __restrict__ routing, const int* __restrict__ perm,
    const float* __restrict__ topkw) {
  __shared__ __align__(16) bf16_t lds[16384];
  if ((int)blockIdx.x < EG2_BLKS) {
    gemm_body<1>(blockIdx.x, EG2_BLKS, lds, Hexp, w2b, b2, slotb, nullptr,
                 routing, perm, topkw, nullptr, nullptr);
  } else {
    gemm_body<2>(blockIdx.x - EG2_BLKS, SG1_BLKS, lds, xb, sw1b, sb1, sHbuf,
                 nullptr, routing, perm, nullptr, nullptr, nullptr);
  }
}

// ---------------------------------------------------------------- launch
extern "C" void kernel_launch(void* const* d_in, const int* in_sizes, int n_in,
                              void* d_out, int out_size, void* d_ws, size_t ws_size,
                              hipStream_t stream) {
  const float* x   = (const float*)d_in[0];
  const float* gw  = (const float*)d_in[1];
  const float* w1  = (const float*)d_in[2];
  const float* b1  = (const float*)d_in[3];
  const float* w2  = (const float*)d_in[4];
  const float* b2  = (const float*)d_in[5];
  const float* sw1 = (const float*)d_in[6];
  const float* sb1 = (const float*)d_in[7];
  const float* sw2 = (const float*)d_in[8];
  const float* sb2 = (const float*)d_in[9];
  float* out = (float*)d_out;

  char* ws = (char*)d_ws;
  bf16_t* xb    = (bf16_t*)(ws);                          // 16 MB  [alive through sG1]
  bf16_t* w1b   = (bf16_t*)(ws + ((size_t)16 << 20));     // 64 MB  [dead after eG1]
  bf16_t* w2b   = (bf16_t*)(ws + ((size_t)80 << 20));     // 64 MB  [dead after eG2]
  bf16_t* sw1b  = (bf16_t*)(ws + ((size_t)144 << 20));    // 8 MB
  bf16_t* sw2b  = (bf16_t*)(ws + ((size_t)152 << 20));    // 8 MB
  bf16_t* Hbuf  = (bf16_t*)(ws + ((size_t)160 << 20));    // 128 MB (16384 x 4096 bf16)
  bf16_t* slotb = (bf16_t*)(ws + ((size_t)16 << 20));     // 32 MB bf16, reuses w1b (dead by eG2)
  float*  topkw = (float*)(ws + ((size_t)288 << 20));     // 64 KB
  int*    slote = (int*)(ws + ((size_t)288 << 20) + 65536);
  int*    perm  = (int*)(ws + ((size_t)288 << 20) + 2 * 65536);
  int*    pos   = (int*)(ws + ((size_t)288 << 20) + 3 * 65536);
  int*    routing = (int*)(ws + ((size_t)288 << 20) + 4 * 65536);

  // optional separate shared-H buffer (64 MB at 304 MB) enabling eG2 || sG1
  const bool bigws = ws_size >= ((size_t)368 << 20);
  bf16_t* sHbuf = bigws ? (bf16_t*)(ws + ((size_t)304 << 20)) : Hbuf;

  // gate + weight conversions in one launch
  prep_kernel<<<GATE_BLKS + CVT_BLKS, 256, 0, stream>>>(x, gw, topkw, slote, xb,
                                                        w1, w2, sw1, sw2, w1b);
  // routing (no global atomics anywhere)
  route_kernel<<<8, 256, 0, stream>>>(slote, routing, perm, pos);

  // expert G1 first (frees w1b for slotb)
  gemm_single<0><<<136 * 32, 256, 0, stream>>>(xb, w1b, b1, Hbuf, nullptr, routing,
                                               perm, nullptr, nullptr, nullptr);
  if (bigws) {
    // eG2 || sG1 concurrently (sG1 writes sHbuf, no aliasing with Hbuf)
    gemm_eg2_sg1<<<EG2_BLKS + SG1_BLKS, 256, 0, stream>>>(Hbuf, w2b, b2, slotb,
                                                          xb, sw1b, sb1, sHbuf,
                                                          routing, perm, topkw);
  } else {
    gemm_single<1><<<EG2_BLKS, 256, 0, stream>>>(Hbuf, w2b, b2, slotb, nullptr,
                                                 routing, perm, topkw, nullptr, nullptr);
    gemm_single<2><<<SG1_BLKS, 256, 0, stream>>>(xb, sw1b, sb1, Hbuf, nullptr,
                                                 routing, perm, nullptr, nullptr, nullptr);
  }
  // shared G2 with fused combine
  gemm_single<3><<<64 * 8, 256, 0, stream>>>(sHbuf, sw2b, sb2, nullptr, out, routing,
                                             perm, nullptr, pos, slotb);
}

// Round 18
// 623.445 us; speedup vs baseline: 1.1156x; 1.0149x over previous
//
#include <hip/hip_runtime.h>
#include <hip/hip_bf16.h>

typedef __bf16 bf16_t;
typedef __bf16 bf16x4 __attribute__((ext_vector_type(4)));
typedef __bf16 bf16x8 __attribute__((ext_vector_type(8)));
typedef float  f32x4  __attribute__((ext_vector_type(4)));

static constexpr int TT = 8192;     // tokens (2*4096)
static constexpr int DD = 1024;
static constexpr int FF = 4096;
static constexpr int NSLOT = 2 * TT;  // 16384 (token, k) slots
static constexpr int GATE_BLKS = TT / 4;            // 2048
static constexpr int W1_CHUNKS  = 8 * FF * DD / 8;  // 4194304
static constexpr int SW1_CHUNKS = FF * DD / 8;      // 524288
static constexpr int CVT1_BLKS  = (W1_CHUNKS + SW1_CHUNKS) / 256;   // 18432
static constexpr int W2_CHUNKS  = 8 * DD * FF / 8;  // 4194304
static constexpr int SW2_CHUNKS = DD * FF / 8;      // 524288
static constexpr int CVT2_BLKS  = (W2_CHUNKS + SW2_CHUNKS) / 256;   // 18432
static constexpr int EG1_BLKS = 136 * 32;           // 4352
static constexpr int EG2_BLKS = 136 * 8;            // 1088
static constexpr int SG1_BLKS = 64 * 32;            // 2048

// routing int-array layout
#define R_COUNTS 0
#define R_OFFSET 8
#define R_TSTART 17
#define R_TOTAL  34
#define R_INTS   40

#define GLL(g, l) __builtin_amdgcn_global_load_lds( \
    (__attribute__((address_space(1))) void*)(g), \
    (__attribute__((address_space(3))) void*)(l), 16, 0, 0)

__device__ __forceinline__ float fast_gelu(float v) {
  float t = -1.5957691216f * v - 0.0713548162f * (v * v * v);
  return v / (1.f + __expf(t));
}

__device__ __forceinline__ void cvt_chunk(const float* __restrict__ src, size_t off,
                                          bf16_t* __restrict__ dst, size_t dof) {
  const float4* s = reinterpret_cast<const float4*>(src) + off * 2;
  float4 a = s[0], b = s[1];
  bf16x8 v;
  v[0] = (bf16_t)a.x; v[1] = (bf16_t)a.y; v[2] = (bf16_t)a.z; v[3] = (bf16_t)a.w;
  v[4] = (bf16_t)b.x; v[5] = (bf16_t)b.y; v[6] = (bf16_t)b.z; v[7] = (bf16_t)b.w;
  *reinterpret_cast<bf16x8*>(dst + dof * 8) = v;
}

// ---------------------------------------------------------------- prep: gate (blocks 0..2047) + w1|sw1 cvt
__global__ __launch_bounds__(256) void prep_kernel(const float* __restrict__ x,
                                                   const float* __restrict__ gw,
                                                   float* __restrict__ topkw,
                                                   int* __restrict__ slote,
                                                   bf16_t* __restrict__ xb,
                                                   const float* __restrict__ w1,
                                                   const float* __restrict__ sw1,
                                                   bf16_t* __restrict__ w1b,
                                                   bf16_t* __restrict__ sw1b) {
  if ((int)blockIdx.x >= GATE_BLKS) {
    size_t i = (size_t)(blockIdx.x - GATE_BLKS) * 256 + threadIdx.x;
    if (i < W1_CHUNKS) cvt_chunk(w1, i, w1b, i);
    else               cvt_chunk(sw1, i - W1_CHUNKS, sw1b, i - W1_CHUNKS);
    return;
  }
  // ---- gate (no atomics; also emits xb)
  int wid = threadIdx.x >> 6, lane = threadIdx.x & 63;
  int t = blockIdx.x * 4 + wid;
  const float4* xv = reinterpret_cast<const float4*>(x + (size_t)t * DD) + lane * 4;
  const float4* gv = reinterpret_cast<const float4*>(gw);
  float acc[8];
  float4 xs[4];
#pragma unroll
  for (int e = 0; e < 8; ++e) acc[e] = 0.f;
#pragma unroll
  for (int i = 0; i < 4; ++i) {
    float4 xi = xv[i];
    xs[i] = xi;
#pragma unroll
    for (int e = 0; e < 8; ++e) {
      float4 g = gv[e * 256 + lane * 4 + i];
      acc[e] += xi.x * g.x + xi.y * g.y + xi.z * g.z + xi.w * g.w;
    }
  }
  {
    bf16x8 lo, hi;
    lo[0]=(bf16_t)xs[0].x; lo[1]=(bf16_t)xs[0].y; lo[2]=(bf16_t)xs[0].z; lo[3]=(bf16_t)xs[0].w;
    lo[4]=(bf16_t)xs[1].x; lo[5]=(bf16_t)xs[1].y; lo[6]=(bf16_t)xs[1].z; lo[7]=(bf16_t)xs[1].w;
    hi[0]=(bf16_t)xs[2].x; hi[1]=(bf16_t)xs[2].y; hi[2]=(bf16_t)xs[2].z; hi[3]=(bf16_t)xs[2].w;
    hi[4]=(bf16_t)xs[3].x; hi[5]=(bf16_t)xs[3].y; hi[6]=(bf16_t)xs[3].z; hi[7]=(bf16_t)xs[3].w;
    bf16_t* d = xb + (size_t)t * DD + lane * 16;
    *reinterpret_cast<bf16x8*>(d) = lo;
    *reinterpret_cast<bf16x8*>(d + 8) = hi;
  }
#pragma unroll
  for (int e = 0; e < 8; ++e)
    for (int off = 32; off; off >>= 1) acc[e] += __shfl_xor(acc[e], off, 64);
  if (lane == 0) {
    float m = acc[0];
#pragma unroll
    for (int e = 1; e < 8; ++e) m = fmaxf(m, acc[e]);
    float p[8], s = 0.f;
#pragma unroll
    for (int e = 0; e < 8; ++e) { p[e] = expf(acc[e] - m); s += p[e]; }
    float inv = 1.f / s;
#pragma unroll
    for (int e = 0; e < 8; ++e) p[e] *= inv;
    int e1 = 0; float b1v = p[0];
#pragma unroll
    for (int e = 1; e < 8; ++e) if (p[e] > b1v) { b1v = p[e]; e1 = e; }
    int e2 = -1; float b2v = -1.f;
#pragma unroll
    for (int e = 0; e < 8; ++e) if (e != e1 && p[e] > b2v) { b2v = p[e]; e2 = e; }
    topkw[2 * t] = b1v;  topkw[2 * t + 1] = b2v;
    slote[2 * t] = e1;   slote[2 * t + 1] = e2;
  }
}

// ---------------------------------------------------------------- fused routing (8 blocks, no atomics)
__global__ __launch_bounds__(256) void route_kernel(const int* __restrict__ slote,
                                                    int* __restrict__ routing,
                                                    int* __restrict__ perm,
                                                    int* __restrict__ pos) {
  __shared__ int sl[16384];   // 64 KB
  __shared__ int red[256];
  __shared__ int wtot[4];
  const int e = blockIdx.x;
  const int t = threadIdx.x;
  const int lane = t & 63, wid = t >> 6;

  for (int i = t; i < NSLOT; i += 256) sl[i] = slote[i];
  __syncthreads();

  int cnt[8];
#pragma unroll
  for (int ee = 0; ee < 8; ++ee) cnt[ee] = 0;
  for (int i = t; i < NSLOT; i += 256) ++cnt[sl[i]];

  int tot[8];
#pragma unroll
  for (int ee = 0; ee < 8; ++ee) {
    red[t] = cnt[ee];
    __syncthreads();
    for (int s = 128; s; s >>= 1) {
      if (t < s) red[t] += red[t + s];
      __syncthreads();
    }
    tot[ee] = red[0];
    __syncthreads();
  }

  int offarr[9], tstart[9];
  {
    int off = 0, tts = 0;
#pragma unroll
    for (int ee = 0; ee < 8; ++ee) {
      offarr[ee] = off; tstart[ee] = tts;
      off += tot[ee]; tts += (tot[ee] + 127) >> 7;
    }
    offarr[8] = off; tstart[8] = tts;
  }
  if (e == 0 && t == 0) {
#pragma unroll
    for (int ee = 0; ee < 8; ++ee) routing[R_COUNTS + ee] = tot[ee];
#pragma unroll
    for (int ee = 0; ee < 9; ++ee) {
      routing[R_OFFSET + ee] = offarr[ee];
      routing[R_TSTART + ee] = tstart[ee];
    }
    routing[R_TOTAL] = tstart[8];
  }

  int running = offarr[e];
  for (int base = 0; base < NSLOT; base += 256) {
    int s = base + t;
    bool m = (sl[s] == e);
    unsigned long long mask = __ballot(m);
    int wrank = __popcll(mask & ((1ull << lane) - 1ull));
    if (lane == 0) wtot[wid] = __popcll(mask);
    __syncthreads();
    int wpre = 0;
#pragma unroll
    for (int w = 0; w < 4; ++w) if (w < wid) wpre += wtot[w];
    int totb = wtot[0] + wtot[1] + wtot[2] + wtot[3];
    if (m) {
      int pp = running + wpre + wrank;
      perm[pp] = s;
      pos[s] = pp;
    }
    running += totb;
    __syncthreads();
  }
}

// ---------------------------------------------------------------- GEMM body (m97 replica loop; frozen)
// 128x128 tile, BK=64, 256 threads / 4 waves (2x2), SINGLE 32 KB LDS buffer.
// Swizzle phys_chunk = log_chunk ^ (row&7), both sides. BK axis closed (R4/R16).
// MODE 0: expert G1 (A via perm, K=1024) -> fast_gelu -> H (bf16)
// MODE 1: expert G2 (A = H rows, K=4096) -> w_slot*(acc+b2) -> slotb (bf16)
// MODE 2: shared G1 (A = x direct, K=1024) -> fast_gelu -> H (bf16)
// MODE 3: shared G2 (A = H rows, K=4096) -> out = acc+sb2+slotb[pos0]+slotb[pos1]
template <int MODE>
__device__ __forceinline__ void gemm_body(
    int vbid, int nwg, bf16_t* lds,
    const bf16_t* __restrict__ A, const bf16_t* __restrict__ Bw,
    const float* __restrict__ bias, bf16_t* __restrict__ Hout,
    float* __restrict__ out, const int* __restrict__ routing,
    const int* __restrict__ perm, const float* __restrict__ topkw,
    const int* __restrict__ pos, const bf16_t* __restrict__ slotb) {
  constexpr bool EXPERT = (MODE < 2);
  constexpr int K = (MODE == 0 || MODE == 2) ? 1024 : 4096;
  constexpr int NTOT = (MODE == 0 || MODE == 2) ? 4096 : 1024;
  constexpr int NT = NTOT / 128;   // 32 or 8 (pow2)
  constexpr int NKT = K / 64;      // 16 or 64
  constexpr int OUTD = (MODE == 0 || MODE == 2) ? FF : DD;

  const int t = threadIdx.x;
  const int lane = t & 63;
  const int wid = t >> 6;          // 0..3
  const int wm = wid >> 1;         // 0..1
  const int wn = wid & 1;          // 0..1

  const int q = nwg >> 3, r = nwg & 7;
  const int xcd = vbid & 7, bi = vbid >> 3;
  const int swz = (xcd < r ? xcd * (q + 1) : r * (q + 1) + (xcd - r) * q) + bi;
  const int mt = swz / NT;
  const int nt = swz & (NT - 1);

  int row0, valid, eidx = 0;
  if constexpr (EXPERT) {
    if (mt >= routing[R_TOTAL]) return;
    int e = 0;
    while (e < 7 && routing[R_TSTART + e + 1] <= mt) ++e;
    eidx = e;
    int lm = mt - routing[R_TSTART + e];
    row0 = routing[R_OFFSET + e] + lm * 128;
    valid = min(128, routing[R_COUNTS + e] - lm * 128);
  } else {
    row0 = mt * 128;
    valid = 128;
  }

  const bf16_t* Bexp = Bw + (EXPERT ? (size_t)eidx * NTOT * K : 0);
  const float* biasp = bias + (EXPERT ? eidx * NTOT : 0);

  const int sub = t >> 3;                     // 0..31
  const int lc = (t & 7) ^ (sub & 7);
  const bf16_t* aS[4];
  const bf16_t* bS[4];
#pragma unroll
  for (int i = 0; i < 4; ++i) {
    int lr = sub + i * 32;                    // 0..127
    int gr;
    if constexpr (MODE == 0) {
      gr = perm[row0 + min(lr, valid - 1)] >> 1;
    } else if constexpr (MODE == 1) {
      gr = row0 + min(lr, valid - 1);
    } else {
      gr = row0 + lr;
    }
    aS[i] = A + (size_t)gr * K + lc * 8;
    bS[i] = Bexp + (size_t)(nt * 128 + lr) * K + lc * 8;
  }
  bf16_t* const aD = lds + (sub << 6) + ((t & 7) << 3);
  bf16_t* const bD = aD + 8192;

  const int l15 = lane & 15, lq = lane >> 4;

  f32x4 acc[4][4];
#pragma unroll
  for (int m = 0; m < 4; ++m)
#pragma unroll
    for (int n = 0; n < 4; ++n) acc[m][n] = f32x4{0.f, 0.f, 0.f, 0.f};

  for (int kt = 0; kt < NKT; ++kt) {
    const size_t kof = (size_t)kt * 64;
#pragma unroll
    for (int i = 0; i < 4; ++i) {
      GLL(aS[i] + kof, aD + i * 2048);
      GLL(bS[i] + kof, bD + i * 2048);
    }
    __syncthreads();

#pragma unroll
    for (int kk = 0; kk < 2; ++kk) {
      bf16x8 af[4], bfr[4];
#pragma unroll
      for (int m = 0; m < 4; ++m) {
        int ra = wm * 64 + m * 16 + l15;
        int ph = (kk * 4 + lq) ^ (ra & 7);
        af[m] = *reinterpret_cast<const bf16x8*>(&lds[ra * 64 + ph * 8]);
      }
#pragma unroll
      for (int n = 0; n < 4; ++n) {
        int rb = wn * 64 + n * 16 + l15;
        int ph = (kk * 4 + lq) ^ (rb & 7);
        bfr[n] = *reinterpret_cast<const bf16x8*>(&lds[8192 + rb * 64 + ph * 8]);
      }
      __builtin_amdgcn_s_setprio(1);
#pragma unroll
      for (int m = 0; m < 4; ++m)
#pragma unroll
        for (int n = 0; n < 4; ++n)
          acc[m][n] = __builtin_amdgcn_mfma_f32_16x16x32_bf16(af[m], bfr[n], acc[m][n], 0, 0, 0);
      __builtin_amdgcn_s_setprio(0);
    }
    __syncthreads();
  }

  float bc[4];
#pragma unroll
  for (int n = 0; n < 4; ++n) bc[n] = biasp[nt * 128 + wn * 64 + n * 16 + l15];

  // ---- epilogue via LDS transpose: coalesced vector stores.
  if constexpr (MODE != 3) {
    bf16_t* scr = lds;   // 64 x 128 bf16 = 16 KB per half
#pragma unroll
    for (int h = 0; h < 2; ++h) {
      __syncthreads();
      if (wm == h) {
        float wsl[4][4];
        if constexpr (MODE == 1) {
#pragma unroll
          for (int m = 0; m < 4; ++m)
#pragma unroll
            for (int rr = 0; rr < 4; ++rr) {
              int lr = h * 64 + m * 16 + lq * 4 + rr;
              wsl[m][rr] = topkw[perm[row0 + min(lr, valid - 1)]];
            }
        }
#pragma unroll
        for (int m = 0; m < 4; ++m)
#pragma unroll
          for (int n = 0; n < 4; ++n)
#pragma unroll
            for (int rr = 0; rr < 4; ++rr) {
              float v = acc[m][n][rr] + bc[n];
              float o;
              if constexpr (MODE == 1) o = wsl[m][rr] * v;
              else                     o = fast_gelu(v);
              scr[(m * 16 + lq * 4 + rr) * 128 + wn * 64 + n * 16 + l15] = (bf16_t)o;
            }
      }
      __syncthreads();
#pragma unroll
      for (int i = 0; i < 4; ++i) {
        int c = t + i * 256;
        int rowp = c >> 4, cc = c & 15;
        int lr = h * 64 + rowp;
        if (lr < valid) {
          bf16x8 v8 = *reinterpret_cast<const bf16x8*>(&scr[rowp * 128 + cc * 8]);
          *reinterpret_cast<bf16x8*>(&Hout[(size_t)(row0 + lr) * OUTD + nt * 128 + cc * 8]) = v8;
        }
      }
    }
  } else {
    float* scr = reinterpret_cast<float*>(lds);   // 64 x 128 f32 = 32 KB per half
#pragma unroll
    for (int h = 0; h < 2; ++h) {
      __syncthreads();
      if (wm == h) {
#pragma unroll
        for (int m = 0; m < 4; ++m)
#pragma unroll
          for (int n = 0; n < 4; ++n)
#pragma unroll
            for (int rr = 0; rr < 4; ++rr)
              scr[(m * 16 + lq * 4 + rr) * 128 + wn * 64 + n * 16 + l15] = acc[m][n][rr] + bc[n];
      }
      __syncthreads();
#pragma unroll
      for (int i = 0; i < 8; ++i) {
        int c = t + i * 256;
        int rowp = c >> 5, cc = c & 31;
        int lr = h * 64 + rowp;
        int gp = row0 + lr;
        int p0 = pos[2 * gp], p1 = pos[2 * gp + 1];
        float4 v4 = *reinterpret_cast<const float4*>(&scr[rowp * 128 + cc * 4]);
        bf16x4 s0 = *reinterpret_cast<const bf16x4*>(&slotb[(size_t)p0 * DD + nt * 128 + cc * 4]);
        bf16x4 s1 = *reinterpret_cast<const bf16x4*>(&slotb[(size_t)p1 * DD + nt * 128 + cc * 4]);
        v4.x += (float)s0[0] + (float)s1[0];
        v4.y += (float)s0[1] + (float)s1[1];
        v4.z += (float)s0[2] + (float)s1[2];
        v4.w += (float)s0[3] + (float)s1[3];
        *reinterpret_cast<float4*>(&out[(size_t)gp * OUTD + nt * 128 + cc * 4]) = v4;
      }
    }
  }
}

// ---------------------------------------------------------------- kernels
template <int MODE>
__global__ __launch_bounds__(256, 4) void gemm_single(
    const bf16_t* __restrict__ A, const bf16_t* __restrict__ Bw,
    const float* __restrict__ bias, bf16_t* __restrict__ Hout,
    float* __restrict__ out, const int* __restrict__ routing,
    const int* __restrict__ perm, const float* __restrict__ topkw,
    const int* __restrict__ pos, const bf16_t* __restrict__ slotb) {
  __shared__ __align__(16) bf16_t lds[16384];
  gemm_body<MODE>(blockIdx.x, gridDim.x, lds, A, Bw, bias, Hout, out,
                  routing, perm, topkw, pos, slotb);
}

// eG1 (blocks 0..EG1_BLKS-1) || w2/sw2 convert (rest) — heterogeneous co-residency
__global__ __launch_bounds__(256, 4) void gemm_eg1_cvt(
    const bf16_t* __restrict__ xb, const bf16_t* __restrict__ w1b,
    const float* __restrict__ b1, bf16_t* __restrict__ Hbuf,
    const int* __restrict__ routing, const int* __restrict__ perm,
    const float* __restrict__ w2, const float* __restrict__ sw2,
    bf16_t* __restrict__ w2b, bf16_t* __restrict__ sw2b) {
  __shared__ __align__(16) bf16_t lds[16384];
  if ((int)blockIdx.x < EG1_BLKS) {
    gemm_body<0>(blockIdx.x, EG1_BLKS, lds, xb, w1b, b1, Hbuf, nullptr,
                 routing, perm, nullptr, nullptr, nullptr);
  } else {
    size_t i = (size_t)(blockIdx.x - EG1_BLKS) * 256 + threadIdx.x;
    if (i < W2_CHUNKS) cvt_chunk(w2, i, w2b, i);
    else               cvt_chunk(sw2, i - W2_CHUNKS, sw2b, i - W2_CHUNKS);
  }
}

// eG2 (blocks 0..EG2_BLKS-1) || sG1 (rest). sG1 writes its own sHbuf.
__global__ __launch_bounds__(256, 4) void gemm_eg2_sg1(
    const bf16_t* __restrict__ Hexp, const bf16_t* __restrict__ w2b,
    const float* __restrict__ b2, bf16_t* __restrict__ slotb,
    const bf16_t* __restrict__ xb, const bf16_t* __restrict__ sw1b,
    const float* __restrict__ sb1, bf16_t* __restrict__ sHbuf,
    const int* __restrict__ routing, const int* __restrict__ perm,
    const float* __restrict__ topkw) {
  __shared__ __align__(16) bf16_t lds[16384];
  if ((int)blockIdx.x < EG2_BLKS) {
    gemm_body<1>(blockIdx.x, EG2_BLKS, lds, Hexp, w2b, b2, slotb, nullptr,
                 routing, perm, topkw, nullptr, nullptr);
  } else {
    gemm_body<2>(blockIdx.x - EG2_BLKS, SG1_BLKS, lds, xb, sw1b, sb1, sHbuf,
                 nullptr, routing, perm, nullptr, nullptr, nullptr);
  }
}

// ---------------------------------------------------------------- launch
extern "C" void kernel_launch(void* const* d_in, const int* in_sizes, int n_in,
                              void* d_out, int out_size, void* d_ws, size_t ws_size,
                              hipStream_t stream) {
  const float* x   = (const float*)d_in[0];
  const float* gw  = (const float*)d_in[1];
  const float* w1  = (const float*)d_in[2];
  const float* b1  = (const float*)d_in[3];
  const float* w2  = (const float*)d_in[4];
  const float* b2  = (const float*)d_in[5];
  const float* sw1 = (const float*)d_in[6];
  const float* sb1 = (const float*)d_in[7];
  const float* sw2 = (const float*)d_in[8];
  const float* sb2 = (const float*)d_in[9];
  float* out = (float*)d_out;

  char* ws = (char*)d_ws;
  bf16_t* xb    = (bf16_t*)(ws);                          // 16 MB  [alive through sG1]
  bf16_t* w1b   = (bf16_t*)(ws + ((size_t)16 << 20));     // 64 MB  [dead after eG1]
  bf16_t* w2b   = (bf16_t*)(ws + ((size_t)80 << 20));     // 64 MB  [dead after eG2]
  bf16_t* sw1b  = (bf16_t*)(ws + ((size_t)144 << 20));    // 8 MB
  bf16_t* sw2b  = (bf16_t*)(ws + ((size_t)152 << 20));    // 8 MB
  bf16_t* Hbuf  = (bf16_t*)(ws + ((size_t)160 << 20));    // 128 MB (16384 x 4096 bf16)
  bf16_t* slotb = (bf16_t*)(ws + ((size_t)16 << 20));     // 32 MB bf16, reuses w1b (dead by eG2)
  float*  topkw = (float*)(ws + ((size_t)288 << 20));     // 64 KB
  int*    slote = (int*)(ws + ((size_t)288 << 20) + 65536);
  int*    perm  = (int*)(ws + ((size_t)288 << 20) + 2 * 65536);
  int*    pos   = (int*)(ws + ((size_t)288 << 20) + 3 * 65536);
  int*    routing = (int*)(ws + ((size_t)288 << 20) + 4 * 65536);

  // optional separate shared-H buffer (64 MB at 304 MB) enabling eG2 || sG1
  const bool bigws = ws_size >= ((size_t)368 << 20);
  bf16_t* sHbuf = bigws ? (bf16_t*)(ws + ((size_t)304 << 20)) : Hbuf;

  // gate + w1|sw1 conversion (only what eG1/sG1 need)
  prep_kernel<<<GATE_BLKS + CVT1_BLKS, 256, 0, stream>>>(x, gw, topkw, slote, xb,
                                                         w1, sw1, w1b, sw1b);
  // routing (no global atomics anywhere)
  route_kernel<<<8, 256, 0, stream>>>(slote, routing, perm, pos);

  // expert G1 || w2/sw2 conversion (cvt fills eG1's tail; w2b ready before eG2)
  gemm_eg1_cvt<<<EG1_BLKS + CVT2_BLKS, 256, 0, stream>>>(xb, w1b, b1, Hbuf, routing,
                                                         perm, w2, sw2, w2b, sw2b);
  if (bigws) {
    // eG2 || sG1 concurrently (sG1 writes sHbuf, no aliasing with Hbuf)
    gemm_eg2_sg1<<<EG2_BLKS + SG1_BLKS, 256, 0, stream>>>(Hbuf, w2b, b2, slotb,
                                                          xb, sw1b, sb1, sHbuf,
                                                          routing, perm, topkw);
  } else {
    gemm_single<1><<<EG2_BLKS, 256, 0, stream>>>(Hbuf, w2b, b2, slotb, nullptr,
                                                 routing, perm, topkw, nullptr, nullptr);
    gemm_single<2><<<SG1_BLKS, 256, 0, stream>>>(xb, sw1b, sb1, Hbuf, nullptr,
                                                 routing, perm, nullptr, nullptr, nullptr);
  }
  // shared G2 with fused combine
  gemm_single<3><<<64 * 8, 256, 0, stream>>>(sHbuf, sw2b, sb2, nullptr, out, routing,
                                             perm, nullptr, pos, slotb);
}

// Round 19
// 614.727 us; speedup vs baseline: 1.1314x; 1.0142x over previous
//
#include <hip/hip_runtime.h>
#include <hip/hip_bf16.h>

typedef __bf16 bf16_t;
typedef __bf16 bf16x4 __attribute__((ext_vector_type(4)));
typedef __bf16 bf16x8 __attribute__((ext_vector_type(8)));
typedef float  f32x4  __attribute__((ext_vector_type(4)));

static constexpr int TT = 8192;     // tokens (2*4096)
static constexpr int DD = 1024;
static constexpr int FF = 4096;
static constexpr int NSLOT = 2 * TT;  // 16384 (token, k) slots
static constexpr int GATE_BLKS = TT / 4;            // 2048
static constexpr int W1_CHUNKS  = 8 * FF * DD / 8;  // 4194304
static constexpr int SW1_CHUNKS = FF * DD / 8;      // 524288
static constexpr int CVT1_BLKS  = (W1_CHUNKS + SW1_CHUNKS) / 256;   // 18432
static constexpr int W2_CHUNKS  = 8 * DD * FF / 8;  // 4194304
static constexpr int SW2_CHUNKS = DD * FF / 8;      // 524288
static constexpr int CVT2_BLKS  = (W2_CHUNKS + SW2_CHUNKS) / 256;   // 18432
static constexpr int EG1_BLKS = 136 * 32;           // 4352
static constexpr int EG2_BLKS = 136 * 8;            // 1088
static constexpr int SG1_BLKS = 64 * 32;            // 2048

// routing int-array layout
#define R_COUNTS 0
#define R_OFFSET 8
#define R_TSTART 17
#define R_TOTAL  34
#define R_INTS   40

#define GLL(g, l) __builtin_amdgcn_global_load_lds( \
    (__attribute__((address_space(1))) void*)(g), \
    (__attribute__((address_space(3))) void*)(l), 16, 0, 0)

__device__ __forceinline__ float fast_gelu(float v) {
  float t = -1.5957691216f * v - 0.0713548162f * (v * v * v);
  return v / (1.f + __expf(t));
}

__device__ __forceinline__ void cvt_chunk(const float* __restrict__ src, size_t off,
                                          bf16_t* __restrict__ dst, size_t dof) {
  const float4* s = reinterpret_cast<const float4*>(src) + off * 2;
  float4 a = s[0], b = s[1];
  bf16x8 v;
  v[0] = (bf16_t)a.x; v[1] = (bf16_t)a.y; v[2] = (bf16_t)a.z; v[3] = (bf16_t)a.w;
  v[4] = (bf16_t)b.x; v[5] = (bf16_t)b.y; v[6] = (bf16_t)b.z; v[7] = (bf16_t)b.w;
  *reinterpret_cast<bf16x8*>(dst + dof * 8) = v;
}

// ---------------------------------------------------------------- prep: gate (blocks 0..2047) + w1|sw1 cvt
__global__ __launch_bounds__(256) void prep_kernel(const float* __restrict__ x,
                                                   const float* __restrict__ gw,
                                                   float* __restrict__ topkw,
                                                   int* __restrict__ slote,
                                                   bf16_t* __restrict__ xb,
                                                   const float* __restrict__ w1,
                                                   const float* __restrict__ sw1,
                                                   bf16_t* __restrict__ w1b,
                                                   bf16_t* __restrict__ sw1b) {
  if ((int)blockIdx.x >= GATE_BLKS) {
    size_t i = (size_t)(blockIdx.x - GATE_BLKS) * 256 + threadIdx.x;
    if (i < W1_CHUNKS) cvt_chunk(w1, i, w1b, i);
    else               cvt_chunk(sw1, i - W1_CHUNKS, sw1b, i - W1_CHUNKS);
    return;
  }
  // ---- gate (no atomics; also emits xb)
  int wid = threadIdx.x >> 6, lane = threadIdx.x & 63;
  int t = blockIdx.x * 4 + wid;
  const float4* xv = reinterpret_cast<const float4*>(x + (size_t)t * DD) + lane * 4;
  const float4* gv = reinterpret_cast<const float4*>(gw);
  float acc[8];
  float4 xs[4];
#pragma unroll
  for (int e = 0; e < 8; ++e) acc[e] = 0.f;
#pragma unroll
  for (int i = 0; i < 4; ++i) {
    float4 xi = xv[i];
    xs[i] = xi;
#pragma unroll
    for (int e = 0; e < 8; ++e) {
      float4 g = gv[e * 256 + lane * 4 + i];
      acc[e] += xi.x * g.x + xi.y * g.y + xi.z * g.z + xi.w * g.w;
    }
  }
  {
    bf16x8 lo, hi;
    lo[0]=(bf16_t)xs[0].x; lo[1]=(bf16_t)xs[0].y; lo[2]=(bf16_t)xs[0].z; lo[3]=(bf16_t)xs[0].w;
    lo[4]=(bf16_t)xs[1].x; lo[5]=(bf16_t)xs[1].y; lo[6]=(bf16_t)xs[1].z; lo[7]=(bf16_t)xs[1].w;
    hi[0]=(bf16_t)xs[2].x; hi[1]=(bf16_t)xs[2].y; hi[2]=(bf16_t)xs[2].z; hi[3]=(bf16_t)xs[2].w;
    hi[4]=(bf16_t)xs[3].x; hi[5]=(bf16_t)xs[3].y; hi[6]=(bf16_t)xs[3].z; hi[7]=(bf16_t)xs[3].w;
    bf16_t* d = xb + (size_t)t * DD + lane * 16;
    *reinterpret_cast<bf16x8*>(d) = lo;
    *reinterpret_cast<bf16x8*>(d + 8) = hi;
  }
#pragma unroll
  for (int e = 0; e < 8; ++e)
    for (int off = 32; off; off >>= 1) acc[e] += __shfl_xor(acc[e], off, 64);
  if (lane == 0) {
    float m = acc[0];
#pragma unroll
    for (int e = 1; e < 8; ++e) m = fmaxf(m, acc[e]);
    float p[8], s = 0.f;
#pragma unroll
    for (int e = 0; e < 8; ++e) { p[e] = expf(acc[e] - m); s += p[e]; }
    float inv = 1.f / s;
#pragma unroll
    for (int e = 0; e < 8; ++e) p[e] *= inv;
    int e1 = 0; float b1v = p[0];
#pragma unroll
    for (int e = 1; e < 8; ++e) if (p[e] > b1v) { b1v = p[e]; e1 = e; }
    int e2 = -1; float b2v = -1.f;
#pragma unroll
    for (int e = 0; e < 8; ++e) if (e != e1 && p[e] > b2v) { b2v = p[e]; e2 = e; }
    topkw[2 * t] = b1v;  topkw[2 * t + 1] = b2v;
    slote[2 * t] = e1;   slote[2 * t + 1] = e2;
  }
}

// ---------------------------------------------------------------- fused routing (8 blocks, no atomics)
__global__ __launch_bounds__(256) void route_kernel(const int* __restrict__ slote,
                                                    int* __restrict__ routing,
                                                    int* __restrict__ perm,
                                                    int* __restrict__ pos) {
  __shared__ int sl[16384];   // 64 KB
  __shared__ int red[256];
  __shared__ int wtot[4];
  const int e = blockIdx.x;
  const int t = threadIdx.x;
  const int lane = t & 63, wid = t >> 6;

  for (int i = t; i < NSLOT; i += 256) sl[i] = slote[i];
  __syncthreads();

  int cnt[8];
#pragma unroll
  for (int ee = 0; ee < 8; ++ee) cnt[ee] = 0;
  for (int i = t; i < NSLOT; i += 256) ++cnt[sl[i]];

  int tot[8];
#pragma unroll
  for (int ee = 0; ee < 8; ++ee) {
    red[t] = cnt[ee];
    __syncthreads();
    for (int s = 128; s; s >>= 1) {
      if (t < s) red[t] += red[t + s];
      __syncthreads();
    }
    tot[ee] = red[0];
    __syncthreads();
  }

  int offarr[9], tstart[9];
  {
    int off = 0, tts = 0;
#pragma unroll
    for (int ee = 0; ee < 8; ++ee) {
      offarr[ee] = off; tstart[ee] = tts;
      off += tot[ee]; tts += (tot[ee] + 127) >> 7;
    }
    offarr[8] = off; tstart[8] = tts;
  }
  if (e == 0 && t == 0) {
#pragma unroll
    for (int ee = 0; ee < 8; ++ee) routing[R_COUNTS + ee] = tot[ee];
#pragma unroll
    for (int ee = 0; ee < 9; ++ee) {
      routing[R_OFFSET + ee] = offarr[ee];
      routing[R_TSTART + ee] = tstart[ee];
    }
    routing[R_TOTAL] = tstart[8];
  }

  int running = offarr[e];
  for (int base = 0; base < NSLOT; base += 256) {
    int s = base + t;
    bool m = (sl[s] == e);
    unsigned long long mask = __ballot(m);
    int wrank = __popcll(mask & ((1ull << lane) - 1ull));
    if (lane == 0) wtot[wid] = __popcll(mask);
    __syncthreads();
    int wpre = 0;
#pragma unroll
    for (int w = 0; w < 4; ++w) if (w < wid) wpre += wtot[w];
    int totb = wtot[0] + wtot[1] + wtot[2] + wtot[3];
    if (m) {
      int pp = running + wpre + wrank;
      perm[pp] = s;
      pos[s] = pp;
    }
    running += totb;
    __syncthreads();
  }
}

// ---------------------------------------------------------------- GEMM body (m97 replica loop; frozen)
// 128x128 tile, BK=64, 256 threads / 4 waves (2x2), SINGLE 32 KB LDS buffer.
// Swizzle phys_chunk = log_chunk ^ (row&7), both sides. BK axis closed (R4/R16).
// Block decode: 8x8 SUPERTILE order (64-block groups touch 8 A-panels + 8 B-panels
// instead of streaming all B panels per mt row) -> cuts LLC-thrash re-fetch.
// MODE 0: expert G1 (A via perm, K=1024) -> fast_gelu -> H (bf16)
// MODE 1: expert G2 (A = H rows, K=4096) -> w_slot*(acc+b2) -> slotb (bf16)
// MODE 2: shared G1 (A = x direct, K=1024) -> fast_gelu -> H (bf16)
// MODE 3: shared G2 (A = H rows, K=4096) -> out = acc+sb2+slotb[pos0]+slotb[pos1]
template <int MODE>
__device__ __forceinline__ void gemm_body(
    int vbid, int nwg, bf16_t* lds,
    const bf16_t* __restrict__ A, const bf16_t* __restrict__ Bw,
    const float* __restrict__ bias, bf16_t* __restrict__ Hout,
    float* __restrict__ out, const int* __restrict__ routing,
    const int* __restrict__ perm, const float* __restrict__ topkw,
    const int* __restrict__ pos, const bf16_t* __restrict__ slotb) {
  constexpr bool EXPERT = (MODE < 2);
  constexpr int K = (MODE == 0 || MODE == 2) ? 1024 : 4096;
  constexpr int NTOT = (MODE == 0 || MODE == 2) ? 4096 : 1024;
  constexpr int NT = NTOT / 128;   // 32 or 8 (pow2)
  constexpr int NTG = NT / 8;      // 4 or 1 (supertile columns)
  constexpr int NKT = K / 64;      // 16 or 64
  constexpr int OUTD = (MODE == 0 || MODE == 2) ? FF : DD;

  const int t = threadIdx.x;
  const int lane = t & 63;
  const int wid = t >> 6;          // 0..3
  const int wm = wid >> 1;         // 0..1
  const int wn = wid & 1;          // 0..1

  const int q = nwg >> 3, r = nwg & 7;
  const int xcd = vbid & 7, bi = vbid >> 3;
  const int swz = (xcd < r ? xcd * (q + 1) : r * (q + 1) + (xcd - r) * q) + bi;
  // 8x8 supertile decode (grids are multiples of 64; mt counts multiples of 8)
  const int sc = swz >> 6;
  const int w64 = swz & 63;
  const int mt = (sc / NTG) * 8 + (w64 & 7);
  const int nt = (sc % NTG) * 8 + (w64 >> 3);

  int row0, valid, eidx = 0;
  if constexpr (EXPERT) {
    if (mt >= routing[R_TOTAL]) return;
    int e = 0;
    while (e < 7 && routing[R_TSTART + e + 1] <= mt) ++e;
    eidx = e;
    int lm = mt - routing[R_TSTART + e];
    row0 = routing[R_OFFSET + e] + lm * 128;
    valid = min(128, routing[R_COUNTS + e] - lm * 128);
  } else {
    row0 = mt * 128;
    valid = 128;
  }

  const bf16_t* Bexp = Bw + (EXPERT ? (size_t)eidx * NTOT * K : 0);
  const float* biasp = bias + (EXPERT ? eidx * NTOT : 0);

  const int sub = t >> 3;                     // 0..31
  const int lc = (t & 7) ^ (sub & 7);
  const bf16_t* aS[4];
  const bf16_t* bS[4];
#pragma unroll
  for (int i = 0; i < 4; ++i) {
    int lr = sub + i * 32;                    // 0..127
    int gr;
    if constexpr (MODE == 0) {
      gr = perm[row0 + min(lr, valid - 1)] >> 1;
    } else if constexpr (MODE == 1) {
      gr = row0 + min(lr, valid - 1);
    } else {
      gr = row0 + lr;
    }
    aS[i] = A + (size_t)gr * K + lc * 8;
    bS[i] = Bexp + (size_t)(nt * 128 + lr) * K + lc * 8;
  }
  bf16_t* const aD = lds + (sub << 6) + ((t & 7) << 3);
  bf16_t* const bD = aD + 8192;

  const int l15 = lane & 15, lq = lane >> 4;

  f32x4 acc[4][4];
#pragma unroll
  for (int m = 0; m < 4; ++m)
#pragma unroll
    for (int n = 0; n < 4; ++n) acc[m][n] = f32x4{0.f, 0.f, 0.f, 0.f};

  for (int kt = 0; kt < NKT; ++kt) {
    const size_t kof = (size_t)kt * 64;
#pragma unroll
    for (int i = 0; i < 4; ++i) {
      GLL(aS[i] + kof, aD + i * 2048);
      GLL(bS[i] + kof, bD + i * 2048);
    }
    __syncthreads();

#pragma unroll
    for (int kk = 0; kk < 2; ++kk) {
      bf16x8 af[4], bfr[4];
#pragma unroll
      for (int m = 0; m < 4; ++m) {
        int ra = wm * 64 + m * 16 + l15;
        int ph = (kk * 4 + lq) ^ (ra & 7);
        af[m] = *reinterpret_cast<const bf16x8*>(&lds[ra * 64 + ph * 8]);
      }
#pragma unroll
      for (int n = 0; n < 4; ++n) {
        int rb = wn * 64 + n * 16 + l15;
        int ph = (kk * 4 + lq) ^ (rb & 7);
        bfr[n] = *reinterpret_cast<const bf16x8*>(&lds[8192 + rb * 64 + ph * 8]);
      }
      __builtin_amdgcn_s_setprio(1);
#pragma unroll
      for (int m = 0; m < 4; ++m)
#pragma unroll
        for (int n = 0; n < 4; ++n)
          acc[m][n] = __builtin_amdgcn_mfma_f32_16x16x32_bf16(af[m], bfr[n], acc[m][n], 0, 0, 0);
      __builtin_amdgcn_s_setprio(0);
    }
    __syncthreads();
  }

  float bc[4];
#pragma unroll
  for (int n = 0; n < 4; ++n) bc[n] = biasp[nt * 128 + wn * 64 + n * 16 + l15];

  // ---- epilogue via LDS transpose: coalesced vector stores.
  if constexpr (MODE != 3) {
    bf16_t* scr = lds;   // 64 x 128 bf16 = 16 KB per half
#pragma unroll
    for (int h = 0; h < 2; ++h) {
      __syncthreads();
      if (wm == h) {
        float wsl[4][4];
        if constexpr (MODE == 1) {
#pragma unroll
          for (int m = 0; m < 4; ++m)
#pragma unroll
            for (int rr = 0; rr < 4; ++rr) {
              int lr = h * 64 + m * 16 + lq * 4 + rr;
              wsl[m][rr] = topkw[perm[row0 + min(lr, valid - 1)]];
            }
        }
#pragma unroll
        for (int m = 0; m < 4; ++m)
#pragma unroll
          for (int n = 0; n < 4; ++n)
#pragma unroll
            for (int rr = 0; rr < 4; ++rr) {
              float v = acc[m][n][rr] + bc[n];
              float o;
              if constexpr (MODE == 1) o = wsl[m][rr] * v;
              else                     o = fast_gelu(v);
              scr[(m * 16 + lq * 4 + rr) * 128 + wn * 64 + n * 16 + l15] = (bf16_t)o;
            }
      }
      __syncthreads();
#pragma unroll
      for (int i = 0; i < 4; ++i) {
        int c = t + i * 256;
        int rowp = c >> 4, cc = c & 15;
        int lr = h * 64 + rowp;
        if (lr < valid) {
          bf16x8 v8 = *reinterpret_cast<const bf16x8*>(&scr[rowp * 128 + cc * 8]);
          *reinterpret_cast<bf16x8*>(&Hout[(size_t)(row0 + lr) * OUTD + nt * 128 + cc * 8]) = v8;
        }
      }
    }
  } else {
    float* scr = reinterpret_cast<float*>(lds);   // 64 x 128 f32 = 32 KB per half
#pragma unroll
    for (int h = 0; h < 2; ++h) {
      __syncthreads();
      if (wm == h) {
#pragma unroll
        for (int m = 0; m < 4; ++m)
#pragma unroll
          for (int n = 0; n < 4; ++n)
#pragma unroll
            for (int rr = 0; rr < 4; ++rr)
              scr[(m * 16 + lq * 4 + rr) * 128 + wn * 64 + n * 16 + l15] = acc[m][n][rr] + bc[n];
      }
      __syncthreads();
#pragma unroll
      for (int i = 0; i < 8; ++i) {
        int c = t + i * 256;
        int rowp = c >> 5, cc = c & 31;
        int lr = h * 64 + rowp;
        int gp = row0 + lr;
        int p0 = pos[2 * gp], p1 = pos[2 * gp + 1];
        float4 v4 = *reinterpret_cast<const float4*>(&scr[rowp * 128 + cc * 4]);
        bf16x4 s0 = *reinterpret_cast<const bf16x4*>(&slotb[(size_t)p0 * DD + nt * 128 + cc * 4]);
        bf16x4 s1 = *reinterpret_cast<const bf16x4*>(&slotb[(size_t)p1 * DD + nt * 128 + cc * 4]);
        v4.x += (float)s0[0] + (float)s1[0];
        v4.y += (float)s0[1] + (float)s1[1];
        v4.z += (float)s0[2] + (float)s1[2];
        v4.w += (float)s0[3] + (float)s1[3];
        *reinterpret_cast<float4*>(&out[(size_t)gp * OUTD + nt * 128 + cc * 4]) = v4;
      }
    }
  }
}

// ---------------------------------------------------------------- kernels
template <int MODE>
__global__ __launch_bounds__(256, 4) void gemm_single(
    const bf16_t* __restrict__ A, const bf16_t* __restrict__ Bw,
    const float* __restrict__ bias, bf16_t* __restrict__ Hout,
    float* __restrict__ out, const int* __restrict__ routing,
    const int* __restrict__ perm, const float* __restrict__ topkw,
    const int* __restrict__ pos, const bf16_t* __restrict__ slotb) {
  __shared__ __align__(16) bf16_t lds[16384];
  gemm_body<MODE>(blockIdx.x, gridDim.x, lds, A, Bw, bias, Hout, out,
                  routing, perm, topkw, pos, slotb);
}

// eG1 (blocks 0..EG1_BLKS-1) || w2/sw2 convert (rest) — heterogeneous co-residency
__global__ __launch_bounds__(256, 4) void gemm_eg1_cvt(
    const bf16_t* __restrict__ xb, const bf16_t* __restrict__ w1b,
    const float* __restrict__ b1, bf16_t* __restrict__ Hbuf,
    const int* __restrict__ routing, const int* __restrict__ perm,
    const float* __restrict__ w2, const float* __restrict__ sw2,
    bf16_t* __restrict__ w2b, bf16_t* __restrict__ sw2b) {
  __shared__ __align__(16) bf16_t lds[16384];
  if ((int)blockIdx.x < EG1_BLKS) {
    gemm_body<0>(blockIdx.x, EG1_BLKS, lds, xb, w1b, b1, Hbuf, nullptr,
                 routing, perm, nullptr, nullptr, nullptr);
  } else {
    size_t i = (size_t)(blockIdx.x - EG1_BLKS) * 256 + threadIdx.x;
    if (i < W2_CHUNKS) cvt_chunk(w2, i, w2b, i);
    else               cvt_chunk(sw2, i - W2_CHUNKS, sw2b, i - W2_CHUNKS);
  }
}

// eG2 (blocks 0..EG2_BLKS-1) || sG1 (rest). sG1 writes its own sHbuf.
__global__ __launch_bounds__(256, 4) void gemm_eg2_sg1(
    const bf16_t* __restrict__ Hexp, const bf16_t* __restrict__ w2b,
    const float* __restrict__ b2, bf16_t* __restrict__ slotb,
    const bf16_t* __restrict__ xb, const bf16_t* __restrict__ sw1b,
    const float* __restrict__ sb1, bf16_t* __restrict__ sHbuf,
    const int* __restrict__ routing, const int* __restrict__ perm,
    const float* __restrict__ topkw) {
  __shared__ __align__(16) bf16_t lds[16384];
  if ((int)blockIdx.x < EG2_BLKS) {
    gemm_body<1>(blockIdx.x, EG2_BLKS, lds, Hexp, w2b, b2, slotb, nullptr,
                 routing, perm, topkw, nullptr, nullptr);
  } else {
    gemm_body<2>(blockIdx.x - EG2_BLKS, SG1_BLKS, lds, xb, sw1b, sb1, sHbuf,
                 nullptr, routing, perm, nullptr, nullptr, nullptr);
  }
}

// ---------------------------------------------------------------- launch
extern "C" void kernel_launch(void* const* d_in, const int* in_sizes, int n_in,
                              void* d_out, int out_size, void* d_ws, size_t ws_size,
                              hipStream_t stream) {
  const float* x   = (const float*)d_in[0];
  const float* gw  = (const float*)d_in[1];
  const float* w1  = (const float*)d_in[2];
  const float* b1  = (const float*)d_in[3];
  const float* w2  = (const float*)d_in[4];
  const float* b2  = (const float*)d_in[5];
  const float* sw1 = (const float*)d_in[6];
  const float* sb1 = (const float*)d_in[7];
  const float* sw2 = (const float*)d_in[8];
  const float* sb2 = (const float*)d_in[9];
  float* out = (float*)d_out;

  char* ws = (char*)d_ws;
  bf16_t* xb    = (bf16_t*)(ws);                          // 16 MB  [alive through sG1]
  bf16_t* w1b   = (bf16_t*)(ws + ((size_t)16 << 20));     // 64 MB  [dead after eG1]
  bf16_t* w2b   = (bf16_t*)(ws + ((size_t)80 << 20));     // 64 MB  [dead after eG2]
  bf16_t* sw1b  = (bf16_t*)(ws + ((size_t)144 << 20));    // 8 MB
  bf16_t* sw2b  = (bf16_t*)(ws + ((size_t)152 << 20));    // 8 MB
  bf16_t* Hbuf  = (bf16_t*)(ws + ((size_t)160 << 20));    // 128 MB (16384 x 4096 bf16)
  bf16_t* slotb = (bf16_t*)(ws + ((size_t)16 << 20));     // 32 MB bf16, reuses w1b (dead by eG2)
  float*  topkw = (float*)(ws + ((size_t)288 << 20));     // 64 KB
  int*    slote = (int*)(ws + ((size_t)288 << 20) + 65536);
  int*    perm  = (int*)(ws + ((size_t)288 << 20) + 2 * 65536);
  int*    pos   = (int*)(ws + ((size_t)288 << 20) + 3 * 65536);
  int*    routing = (int*)(ws + ((size_t)288 << 20) + 4 * 65536);

  // optional separate shared-H buffer (64 MB at 304 MB) enabling eG2 || sG1
  const bool bigws = ws_size >= ((size_t)368 << 20);
  bf16_t* sHbuf = bigws ? (bf16_t*)(ws + ((size_t)304 << 20)) : Hbuf;

  // gate + w1|sw1 conversion (only what eG1/sG1 need)
  prep_kernel<<<GATE_BLKS + CVT1_BLKS, 256, 0, stream>>>(x, gw, topkw, slote, xb,
                                                         w1, sw1, w1b, sw1b);
  // routing (no global atomics anywhere)
  route_kernel<<<8, 256, 0, stream>>>(slote, routing, perm, pos);

  // expert G1 || w2/sw2 conversion (cvt fills eG1's tail; w2b ready before eG2)
  gemm_eg1_cvt<<<EG1_BLKS + CVT2_BLKS, 256, 0, stream>>>(xb, w1b, b1, Hbuf, routing,
                                                         perm, w2, sw2, w2b, sw2b);
  if (bigws) {
    // eG2 || sG1 concurrently (sG1 writes sHbuf, no aliasing with Hbuf)
    gemm_eg2_sg1<<<EG2_BLKS + SG1_BLKS, 256, 0, stream>>>(Hbuf, w2b, b2, slotb,
                                                          xb, sw1b, sb1, sHbuf,
                                                          routing, perm, topkw);
  } else {
    gemm_single<1><<<EG2_BLKS, 256, 0, stream>>>(Hbuf, w2b, b2, slotb, nullptr,
                                                 routing, perm, topkw, nullptr, nullptr);
    gemm_single<2><<<SG1_BLKS, 256, 0, stream>>>(xb, sw1b, sb1, Hbuf, nullptr,
                                                 routing, perm, nullptr, nullptr, nullptr);
  }
  // shared G2 with fused combine
  gemm_single<3><<<64 * 8, 256, 0, stream>>>(sHbuf, sw2b, sb2, nullptr, out, routing,
                                             perm, nullptr, pos, slotb);
}

// Round 20
// 608.071 us; speedup vs baseline: 1.1438x; 1.0109x over previous
//
#include <hip/hip_runtime.h>
#include <hip/hip_bf16.h>

typedef __bf16 bf16_t;
typedef __bf16 bf16x4 __attribute__((ext_vector_type(4)));
typedef __bf16 bf16x8 __attribute__((ext_vector_type(8)));
typedef float  f32x4  __attribute__((ext_vector_type(4)));

static constexpr int TT = 8192;     // tokens (2*4096)
static constexpr int DD = 1024;
static constexpr int FF = 4096;
static constexpr int NSLOT = 2 * TT;  // 16384 (token, k) slots
static constexpr int GATE_BLKS = TT / 4;            // 2048
static constexpr int W1_CHUNKS  = 8 * FF * DD / 8;  // 4194304
static constexpr int SW1_CHUNKS = FF * DD / 8;      // 524288
static constexpr int CVT1_BLKS  = (W1_CHUNKS + SW1_CHUNKS) / 256;   // 18432
static constexpr int W2_CHUNKS  = 8 * DD * FF / 8;  // 4194304
static constexpr int SW2_CHUNKS = DD * FF / 8;      // 524288
static constexpr int CVT2_BLKS  = (W2_CHUNKS + SW2_CHUNKS) / 256;   // 18432
static constexpr int EG1_BLKS = 136 * 32;           // 4352
static constexpr int EG2_BLKS = 136 * 8;            // 1088
static constexpr int SG1_BLKS = 64 * 32;            // 2048

// routing int-array layout
#define R_COUNTS 0
#define R_OFFSET 8
#define R_TSTART 17
#define R_TOTAL  34
#define R_INTS   40

#define GLL(g, l) __builtin_amdgcn_global_load_lds( \
    (__attribute__((address_space(1))) void*)(g), \
    (__attribute__((address_space(3))) void*)(l), 16, 0, 0)

__device__ __forceinline__ float fast_gelu(float v) {
  float t = -1.5957691216f * v - 0.0713548162f * (v * v * v);
  return v / (1.f + __expf(t));
}

__device__ __forceinline__ void cvt_chunk(const float* __restrict__ src, size_t off,
                                          bf16_t* __restrict__ dst, size_t dof) {
  const float4* s = reinterpret_cast<const float4*>(src) + off * 2;
  float4 a = s[0], b = s[1];
  bf16x8 v;
  v[0] = (bf16_t)a.x; v[1] = (bf16_t)a.y; v[2] = (bf16_t)a.z; v[3] = (bf16_t)a.w;
  v[4] = (bf16_t)b.x; v[5] = (bf16_t)b.y; v[6] = (bf16_t)b.z; v[7] = (bf16_t)b.w;
  *reinterpret_cast<bf16x8*>(dst + dof * 8) = v;
}

// ---------------------------------------------------------------- gate (no atomics; also emits xb)
__global__ __launch_bounds__(256) void gate_kernel(const float* __restrict__ x,
                                                   const float* __restrict__ gw,
                                                   float* __restrict__ topkw,
                                                   int* __restrict__ slote,
                                                   bf16_t* __restrict__ xb) {
  int wid = threadIdx.x >> 6, lane = threadIdx.x & 63;
  int t = blockIdx.x * 4 + wid;
  const float4* xv = reinterpret_cast<const float4*>(x + (size_t)t * DD) + lane * 4;
  const float4* gv = reinterpret_cast<const float4*>(gw);
  float acc[8];
  float4 xs[4];
#pragma unroll
  for (int e = 0; e < 8; ++e) acc[e] = 0.f;
#pragma unroll
  for (int i = 0; i < 4; ++i) {
    float4 xi = xv[i];
    xs[i] = xi;
#pragma unroll
    for (int e = 0; e < 8; ++e) {
      float4 g = gv[e * 256 + lane * 4 + i];
      acc[e] += xi.x * g.x + xi.y * g.y + xi.z * g.z + xi.w * g.w;
    }
  }
  {
    bf16x8 lo, hi;
    lo[0]=(bf16_t)xs[0].x; lo[1]=(bf16_t)xs[0].y; lo[2]=(bf16_t)xs[0].z; lo[3]=(bf16_t)xs[0].w;
    lo[4]=(bf16_t)xs[1].x; lo[5]=(bf16_t)xs[1].y; lo[6]=(bf16_t)xs[1].z; lo[7]=(bf16_t)xs[1].w;
    hi[0]=(bf16_t)xs[2].x; hi[1]=(bf16_t)xs[2].y; hi[2]=(bf16_t)xs[2].z; hi[3]=(bf16_t)xs[2].w;
    hi[4]=(bf16_t)xs[3].x; hi[5]=(bf16_t)xs[3].y; hi[6]=(bf16_t)xs[3].z; hi[7]=(bf16_t)xs[3].w;
    bf16_t* d = xb + (size_t)t * DD + lane * 16;
    *reinterpret_cast<bf16x8*>(d) = lo;
    *reinterpret_cast<bf16x8*>(d + 8) = hi;
  }
#pragma unroll
  for (int e = 0; e < 8; ++e)
    for (int off = 32; off; off >>= 1) acc[e] += __shfl_xor(acc[e], off, 64);
  if (lane == 0) {
    float m = acc[0];
#pragma unroll
    for (int e = 1; e < 8; ++e) m = fmaxf(m, acc[e]);
    float p[8], s = 0.f;
#pragma unroll
    for (int e = 0; e < 8; ++e) { p[e] = expf(acc[e] - m); s += p[e]; }
    float inv = 1.f / s;
#pragma unroll
    for (int e = 0; e < 8; ++e) p[e] *= inv;
    int e1 = 0; float b1v = p[0];
#pragma unroll
    for (int e = 1; e < 8; ++e) if (p[e] > b1v) { b1v = p[e]; e1 = e; }
    int e2 = -1; float b2v = -1.f;
#pragma unroll
    for (int e = 0; e < 8; ++e) if (e != e1 && p[e] > b2v) { b2v = p[e]; e2 = e; }
    topkw[2 * t] = b1v;  topkw[2 * t + 1] = b2v;
    slote[2 * t] = e1;   slote[2 * t + 1] = e2;
  }
}

// ---------------------------------------------------------------- route (blocks 0..7) || w1/sw1 cvt (rest)
__global__ __launch_bounds__(256) void route_cvt1_kernel(const int* __restrict__ slote,
                                                         int* __restrict__ routing,
                                                         int* __restrict__ perm,
                                                         int* __restrict__ pos,
                                                         const float* __restrict__ w1,
                                                         const float* __restrict__ sw1,
                                                         bf16_t* __restrict__ w1b,
                                                         bf16_t* __restrict__ sw1b) {
  if ((int)blockIdx.x >= 8) {
    size_t i = (size_t)(blockIdx.x - 8) * 256 + threadIdx.x;
    if (i < W1_CHUNKS) cvt_chunk(w1, i, w1b, i);
    else               cvt_chunk(sw1, i - W1_CHUNKS, sw1b, i - W1_CHUNKS);
    return;
  }
  // ---- fused routing (8 blocks, stable, no atomics)
  __shared__ int sl[16384];   // 64 KB
  __shared__ int red[256];
  __shared__ int wtot[4];
  const int e = blockIdx.x;
  const int t = threadIdx.x;
  const int lane = t & 63, wid = t >> 6;

  for (int i = t; i < NSLOT; i += 256) sl[i] = slote[i];
  __syncthreads();

  int cnt[8];
#pragma unroll
  for (int ee = 0; ee < 8; ++ee) cnt[ee] = 0;
  for (int i = t; i < NSLOT; i += 256) ++cnt[sl[i]];

  int tot[8];
#pragma unroll
  for (int ee = 0; ee < 8; ++ee) {
    red[t] = cnt[ee];
    __syncthreads();
    for (int s = 128; s; s >>= 1) {
      if (t < s) red[t] += red[t + s];
      __syncthreads();
    }
    tot[ee] = red[0];
    __syncthreads();
  }

  int offarr[9], tstart[9];
  {
    int off = 0, tts = 0;
#pragma unroll
    for (int ee = 0; ee < 8; ++ee) {
      offarr[ee] = off; tstart[ee] = tts;
      off += tot[ee]; tts += (tot[ee] + 127) >> 7;
    }
    offarr[8] = off; tstart[8] = tts;
  }
  if (e == 0 && t == 0) {
#pragma unroll
    for (int ee = 0; ee < 8; ++ee) routing[R_COUNTS + ee] = tot[ee];
#pragma unroll
    for (int ee = 0; ee < 9; ++ee) {
      routing[R_OFFSET + ee] = offarr[ee];
      routing[R_TSTART + ee] = tstart[ee];
    }
    routing[R_TOTAL] = tstart[8];
  }

  int running = offarr[e];
  for (int base = 0; base < NSLOT; base += 256) {
    int s = base + t;
    bool m = (sl[s] == e);
    unsigned long long mask = __ballot(m);
    int wrank = __popcll(mask & ((1ull << lane) - 1ull));
    if (lane == 0) wtot[wid] = __popcll(mask);
    __syncthreads();
    int wpre = 0;
#pragma unroll
    for (int w = 0; w < 4; ++w) if (w < wid) wpre += wtot[w];
    int totb = wtot[0] + wtot[1] + wtot[2] + wtot[3];
    if (m) {
      int pp = running + wpre + wrank;
      perm[pp] = s;
      pos[s] = pp;
    }
    running += totb;
    __syncthreads();
  }
}

// ---------------------------------------------------------------- GEMM body (m97 replica loop; frozen)
// 128x128 tile, BK=64, 256 threads / 4 waves (2x2), SINGLE 32 KB LDS buffer.
// Swizzle phys_chunk = log_chunk ^ (row&7), both sides. 8x8 supertile decode.
// PRIO: wrap MFMA in s_setprio(1) — enabled only for the long-K role in merged
// dispatches (T5: scheduler favors matrix work when roles differ).
// MODE 0: expert G1 (A via perm, K=1024) -> fast_gelu -> H (bf16)
// MODE 1: expert G2 (A = H rows, K=4096) -> w_slot*(acc+b2) -> slotb (bf16)
// MODE 2: shared G1 (A = x direct, K=1024) -> fast_gelu -> H (bf16)
// MODE 3: shared G2 (A = H rows, K=4096) -> out = acc+sb2+slotb[pos0]+slotb[pos1]
template <int MODE, bool PRIO = true>
__device__ __forceinline__ void gemm_body(
    int vbid, int nwg, bf16_t* lds,
    const bf16_t* __restrict__ A, const bf16_t* __restrict__ Bw,
    const float* __restrict__ bias, bf16_t* __restrict__ Hout,
    float* __restrict__ out, const int* __restrict__ routing,
    const int* __restrict__ perm, const float* __restrict__ topkw,
    const int* __restrict__ pos, const bf16_t* __restrict__ slotb) {
  constexpr bool EXPERT = (MODE < 2);
  constexpr int K = (MODE == 0 || MODE == 2) ? 1024 : 4096;
  constexpr int NTOT = (MODE == 0 || MODE == 2) ? 4096 : 1024;
  constexpr int NT = NTOT / 128;   // 32 or 8 (pow2)
  constexpr int NTG = NT / 8;      // 4 or 1 (supertile columns)
  constexpr int NKT = K / 64;      // 16 or 64
  constexpr int OUTD = (MODE == 0 || MODE == 2) ? FF : DD;

  const int t = threadIdx.x;
  const int lane = t & 63;
  const int wid = t >> 6;          // 0..3
  const int wm = wid >> 1;         // 0..1
  const int wn = wid & 1;          // 0..1

  const int q = nwg >> 3, r = nwg & 7;
  const int xcd = vbid & 7, bi = vbid >> 3;
  const int swz = (xcd < r ? xcd * (q + 1) : r * (q + 1) + (xcd - r) * q) + bi;
  // 8x8 supertile decode (grids are multiples of 64; mt counts multiples of 8)
  const int sc = swz >> 6;
  const int w64 = swz & 63;
  const int mt = (sc / NTG) * 8 + (w64 & 7);
  const int nt = (sc % NTG) * 8 + (w64 >> 3);

  int row0, valid, eidx = 0;
  if constexpr (EXPERT) {
    if (mt >= routing[R_TOTAL]) return;
    int e = 0;
    while (e < 7 && routing[R_TSTART + e + 1] <= mt) ++e;
    eidx = e;
    int lm = mt - routing[R_TSTART + e];
    row0 = routing[R_OFFSET + e] + lm * 128;
    valid = min(128, routing[R_COUNTS + e] - lm * 128);
  } else {
    row0 = mt * 128;
    valid = 128;
  }

  const bf16_t* Bexp = Bw + (EXPERT ? (size_t)eidx * NTOT * K : 0);
  const float* biasp = bias + (EXPERT ? eidx * NTOT : 0);

  const int sub = t >> 3;                     // 0..31
  const int lc = (t & 7) ^ (sub & 7);
  const bf16_t* aS[4];
  const bf16_t* bS[4];
#pragma unroll
  for (int i = 0; i < 4; ++i) {
    int lr = sub + i * 32;                    // 0..127
    int gr;
    if constexpr (MODE == 0) {
      gr = perm[row0 + min(lr, valid - 1)] >> 1;
    } else if constexpr (MODE == 1) {
      gr = row0 + min(lr, valid - 1);
    } else {
      gr = row0 + lr;
    }
    aS[i] = A + (size_t)gr * K + lc * 8;
    bS[i] = Bexp + (size_t)(nt * 128 + lr) * K + lc * 8;
  }
  bf16_t* const aD = lds + (sub << 6) + ((t & 7) << 3);
  bf16_t* const bD = aD + 8192;

  const int l15 = lane & 15, lq = lane >> 4;

  f32x4 acc[4][4];
#pragma unroll
  for (int m = 0; m < 4; ++m)
#pragma unroll
    for (int n = 0; n < 4; ++n) acc[m][n] = f32x4{0.f, 0.f, 0.f, 0.f};

  for (int kt = 0; kt < NKT; ++kt) {
    const size_t kof = (size_t)kt * 64;
#pragma unroll
    for (int i = 0; i < 4; ++i) {
      GLL(aS[i] + kof, aD + i * 2048);
      GLL(bS[i] + kof, bD + i * 2048);
    }
    __syncthreads();

#pragma unroll
    for (int kk = 0; kk < 2; ++kk) {
      bf16x8 af[4], bfr[4];
#pragma unroll
      for (int m = 0; m < 4; ++m) {
        int ra = wm * 64 + m * 16 + l15;
        int ph = (kk * 4 + lq) ^ (ra & 7);
        af[m] = *reinterpret_cast<const bf16x8*>(&lds[ra * 64 + ph * 8]);
      }
#pragma unroll
      for (int n = 0; n < 4; ++n) {
        int rb = wn * 64 + n * 16 + l15;
        int ph = (kk * 4 + lq) ^ (rb & 7);
        bfr[n] = *reinterpret_cast<const bf16x8*>(&lds[8192 + rb * 64 + ph * 8]);
      }
      if constexpr (PRIO) __builtin_amdgcn_s_setprio(1);
#pragma unroll
      for (int m = 0; m < 4; ++m)
#pragma unroll
        for (int n = 0; n < 4; ++n)
          acc[m][n] = __builtin_amdgcn_mfma_f32_16x16x32_bf16(af[m], bfr[n], acc[m][n], 0, 0, 0);
      if constexpr (PRIO) __builtin_amdgcn_s_setprio(0);
    }
    __syncthreads();
  }

  float bc[4];
#pragma unroll
  for (int n = 0; n < 4; ++n) bc[n] = biasp[nt * 128 + wn * 64 + n * 16 + l15];

  // ---- epilogue via LDS transpose: coalesced vector stores.
  if constexpr (MODE != 3) {
    bf16_t* scr = lds;   // 64 x 128 bf16 = 16 KB per half
#pragma unroll
    for (int h = 0; h < 2; ++h) {
      __syncthreads();
      if (wm == h) {
        float wsl[4][4];
        if constexpr (MODE == 1) {
#pragma unroll
          for (int m = 0; m < 4; ++m)
#pragma unroll
            for (int rr = 0; rr < 4; ++rr) {
              int lr = h * 64 + m * 16 + lq * 4 + rr;
              wsl[m][rr] = topkw[perm[row0 + min(lr, valid - 1)]];
            }
        }
#pragma unroll
        for (int m = 0; m < 4; ++m)
#pragma unroll
          for (int n = 0; n < 4; ++n)
#pragma unroll
            for (int rr = 0; rr < 4; ++rr) {
              float v = acc[m][n][rr] + bc[n];
              float o;
              if constexpr (MODE == 1) o = wsl[m][rr] * v;
              else                     o = fast_gelu(v);
              scr[(m * 16 + lq * 4 + rr) * 128 + wn * 64 + n * 16 + l15] = (bf16_t)o;
            }
      }
      __syncthreads();
#pragma unroll
      for (int i = 0; i < 4; ++i) {
        int c = t + i * 256;
        int rowp = c >> 4, cc = c & 15;
        int lr = h * 64 + rowp;
        if (lr < valid) {
          bf16x8 v8 = *reinterpret_cast<const bf16x8*>(&scr[rowp * 128 + cc * 8]);
          *reinterpret_cast<bf16x8*>(&Hout[(size_t)(row0 + lr) * OUTD + nt * 128 + cc * 8]) = v8;
        }
      }
    }
  } else {
    float* scr = reinterpret_cast<float*>(lds);   // 64 x 128 f32 = 32 KB per half
#pragma unroll
    for (int h = 0; h < 2; ++h) {
      __syncthreads();
      if (wm == h) {
#pragma unroll
        for (int m = 0; m < 4; ++m)
#pragma unroll
          for (int n = 0; n < 4; ++n)
#pragma unroll
            for (int rr = 0; rr < 4; ++rr)
              scr[(m * 16 + lq * 4 + rr) * 128 + wn * 64 + n * 16 + l15] = acc[m][n][rr] + bc[n];
      }
      __syncthreads();
#pragma unroll
      for (int i = 0; i < 8; ++i) {
        int c = t + i * 256;
        int rowp = c >> 5, cc = c & 31;
        int lr = h * 64 + rowp;
        int gp = row0 + lr;
        int p0 = pos[2 * gp], p1 = pos[2 * gp + 1];
        float4 v4 = *reinterpret_cast<const float4*>(&scr[rowp * 128 + cc * 4]);
        bf16x4 s0 = *reinterpret_cast<const bf16x4*>(&slotb[(size_t)p0 * DD + nt * 128 + cc * 4]);
        bf16x4 s1 = *reinterpret_cast<const bf16x4*>(&slotb[(size_t)p1 * DD + nt * 128 + cc * 4]);
        v4.x += (float)s0[0] + (float)s1[0];
        v4.y += (float)s0[1] + (float)s1[1];
        v4.z += (float)s0[2] + (float)s1[2];
        v4.w += (float)s0[3] + (float)s1[3];
        *reinterpret_cast<float4*>(&out[(size_t)gp * OUTD + nt * 128 + cc * 4]) = v4;
      }
    }
  }
}

// ---------------------------------------------------------------- kernels
template <int MODE>
__global__ __launch_bounds__(256, 4) void gemm_single(
    const bf16_t* __restrict__ A, const bf16_t* __restrict__ Bw,
    const float* __restrict__ bias, bf16_t* __restrict__ Hout,
    float* __restrict__ out, const int* __restrict__ routing,
    const int* __restrict__ perm, const float* __restrict__ topkw,
    const int* __restrict__ pos, const bf16_t* __restrict__ slotb) {
  __shared__ __align__(16) bf16_t lds[16384];
  gemm_body<MODE>(blockIdx.x, gridDim.x, lds, A, Bw, bias, Hout, out,
                  routing, perm, topkw, pos, slotb);
}

// eG1 (blocks 0..EG1_BLKS-1) || w2/sw2 convert (rest) — heterogeneous co-residency
__global__ __launch_bounds__(256, 4) void gemm_eg1_cvt(
    const bf16_t* __restrict__ xb, const bf16_t* __restrict__ w1b,
    const float* __restrict__ b1, bf16_t* __restrict__ Hbuf,
    const int* __restrict__ routing, const int* __restrict__ perm,
    const float* __restrict__ w2, const float* __restrict__ sw2,
    bf16_t* __restrict__ w2b, bf16_t* __restrict__ sw2b) {
  __shared__ __align__(16) bf16_t lds[16384];
  if ((int)blockIdx.x < EG1_BLKS) {
    gemm_body<0>(blockIdx.x, EG1_BLKS, lds, xb, w1b, b1, Hbuf, nullptr,
                 routing, perm, nullptr, nullptr, nullptr);
  } else {
    size_t i = (size_t)(blockIdx.x - EG1_BLKS) * 256 + threadIdx.x;
    if (i < W2_CHUNKS) cvt_chunk(w2, i, w2b, i);
    else               cvt_chunk(sw2, i - W2_CHUNKS, sw2b, i - W2_CHUNKS);
  }
}

// eG2 (blocks 0..EG2_BLKS-1, PRIO) || sG1 (rest, no-PRIO). sG1 writes its own sHbuf.
__global__ __launch_bounds__(256, 4) void gemm_eg2_sg1(
    const bf16_t* __restrict__ Hexp, const bf16_t* __restrict__ w2b,
    const float* __restrict__ b2, bf16_t* __restrict__ slotb,
    const bf16_t* __restrict__ xb, const bf16_t* __restrict__ sw1b,
    const float* __restrict__ sb1, bf16_t* __restrict__ sHbuf,
    const int* __restrict__ routing, const int* __restrict__ perm,
    const float* __restrict__ topkw) {
  __shared__ __align__(16) bf16_t lds[16384];
  if ((int)blockIdx.x < EG2_BLKS) {
    gemm_body<1, true>(blockIdx.x, EG2_BLKS, lds, Hexp, w2b, b2, slotb, nullptr,
                       routing, perm, topkw, nullptr, nullptr);
  } else {
    gemm_body<2, false>(blockIdx.x - EG2_BLKS, SG1_BLKS, lds, xb, sw1b, sb1, sHbuf,
                        nullptr, routing, perm, nullptr, nullptr, nullptr);
  }
}

// ---------------------------------------------------------------- launch
extern "C" void kernel_launch(void* const* d_in, const int* in_sizes, int n_in,
                              void* d_out, int out_size, void* d_ws, size_t ws_size,
                              hipStream_t stream) {
  const float* x   = (const float*)d_in[0];
  const float* gw  = (const float*)d_in[1];
  const float* w1  = (const float*)d_in[2];
  const float* b1  = (const float*)d_in[3];
  const float* w2  = (const float*)d_in[4];
  const float* b2  = (const float*)d_in[5];
  const float* sw1 = (const float*)d_in[6];
  const float* sb1 = (const float*)d_in[7];
  const float* sw2 = (const float*)d_in[8];
  const float* sb2 = (const float*)d_in[9];
  float* out = (float*)d_out;

  char* ws = (char*)d_ws;
  bf16_t* xb    = (bf16_t*)(ws);                          // 16 MB  [alive through sG1]
  bf16_t* w1b   = (bf16_t*)(ws + ((size_t)16 << 20));     // 64 MB  [dead after eG1]
  bf16_t* w2b   = (bf16_t*)(ws + ((size_t)80 << 20));     // 64 MB  [dead after eG2]
  bf16_t* sw1b  = (bf16_t*)(ws + ((size_t)144 << 20));    // 8 MB
  bf16_t* sw2b  = (bf16_t*)(ws + ((size_t)152 << 20));    // 8 MB
  bf16_t* Hbuf  = (bf16_t*)(ws + ((size_t)160 << 20));    // 128 MB (16384 x 4096 bf16)
  bf16_t* slotb = (bf16_t*)(ws + ((size_t)16 << 20));     // 32 MB bf16, reuses w1b (dead by eG2)
  float*  topkw = (float*)(ws + ((size_t)288 << 20));     // 64 KB
  int*    slote = (int*)(ws + ((size_t)288 << 20) + 65536);
  int*    perm  = (int*)(ws + ((size_t)288 << 20) + 2 * 65536);
  int*    pos   = (int*)(ws + ((size_t)288 << 20) + 3 * 65536);
  int*    routing = (int*)(ws + ((size_t)288 << 20) + 4 * 65536);

  // optional separate shared-H buffer (64 MB at 304 MB) enabling eG2 || sG1
  const bool bigws = ws_size >= ((size_t)368 << 20);
  bf16_t* sHbuf = bigws ? (bf16_t*)(ws + ((size_t)304 << 20)) : Hbuf;

  // gate only (fast), then routing hidden under w1/sw1 conversion
  gate_kernel<<<GATE_BLKS, 256, 0, stream>>>(x, gw, topkw, slote, xb);
  route_cvt1_kernel<<<8 + CVT1_BLKS, 256, 0, stream>>>(slote, routing, perm, pos,
                                                       w1, sw1, w1b, sw1b);

  // expert G1 || w2/sw2 conversion (cvt fills eG1's tail; w2b ready before eG2)
  gemm_eg1_cvt<<<EG1_BLKS + CVT2_BLKS, 256, 0, stream>>>(xb, w1b, b1, Hbuf, routing,
                                                         perm, w2, sw2, w2b, sw2b);
  if (bigws) {
    // eG2 || sG1 concurrently (sG1 writes sHbuf, no aliasing with Hbuf)
    gemm_eg2_sg1<<<EG2_BLKS + SG1_BLKS, 256, 0, stream>>>(Hbuf, w2b, b2, slotb,
                                                          xb, sw1b, sb1, sHbuf,
                                                          routing, perm, topkw);
  } else {
    gemm_single<1><<<EG2_BLKS, 256, 0, stream>>>(Hbuf, w2b, b2, slotb, nullptr,
                                                 routing, perm, topkw, nullptr, nullptr);
    gemm_single<2><<<SG1_BLKS, 256, 0, stream>>>(xb, sw1b, sb1, Hbuf, nullptr,
                                                 routing, perm, nullptr, nullptr, nullptr);
  }
  // shared G2 with fused combine
  gemm_single<3><<<64 * 8, 256, 0, stream>>>(sHbuf, sw2b, sb2, nullptr, out, routing,
                                             perm, nullptr, pos, slotb);
}